// Round 16
// baseline (888.046 us; speedup 1.0000x reference)
//
#include <hip/hip_runtime.h>
#include <stdint.h>

typedef __bf16 bf16;
typedef __attribute__((ext_vector_type(8))) __bf16 bf16x8;
typedef __attribute__((ext_vector_type(4))) float f32x4;

namespace {

constexpr int cB = 4, cT = 4096, cD = 2048, cK = 1024, cH = 16, cKVH = 4, cHD = 128, cFF = 8192;
constexpr int cM = cB * cK;                 // 4096 gathered rows
constexpr int QKVW = cH * cHD + 2 * cKVH * cHD; // 3072

__device__ __forceinline__ void load_lds16(const void* g, void* l) {
  __builtin_amdgcn_global_load_lds((const __attribute__((address_space(1))) void*)g,
                                   (__attribute__((address_space(3))) void*)l, 16, 0, 0);
}

template <int N>
__device__ __forceinline__ void waitcnt_vm() {
  if constexpr (N == 0) asm volatile("s_waitcnt vmcnt(0)" ::: "memory");
  else if constexpr (N == 1) asm volatile("s_waitcnt vmcnt(1)" ::: "memory");
  else if constexpr (N == 2) asm volatile("s_waitcnt vmcnt(2)" ::: "memory");
  else if constexpr (N == 3) asm volatile("s_waitcnt vmcnt(3)" ::: "memory");
  else if constexpr (N == 4) asm volatile("s_waitcnt vmcnt(4)" ::: "memory");
  else if constexpr (N == 6) asm volatile("s_waitcnt vmcnt(6)" ::: "memory");
  else if constexpr (N == 8) asm volatile("s_waitcnt vmcnt(8)" ::: "memory");
  else static_assert(N == 0, "unsupported vmcnt literal");
}

// ---------------- block reduce (256 threads = 4 waves) ----------------
template <int OP>  // 0 = sum, 1 = max
__device__ __forceinline__ float blk_reduce(float v) {
  __shared__ float sm[5];
  const int tid = threadIdx.x, lane = tid & 63, wid = tid >> 6;
#pragma unroll
  for (int o = 32; o; o >>= 1) {
    float o2 = __shfl_down(v, o, 64);
    v = OP ? fmaxf(v, o2) : v + o2;
  }
  if (lane == 0) sm[wid] = v;
  __syncthreads();
  if (tid == 0) {
    float r = sm[0];
#pragma unroll
    for (int i = 1; i < 4; ++i) r = OP ? fmaxf(r, sm[i]) : r + sm[i];
    sm[4] = r;
  }
  __syncthreads();
  float r = sm[4];
  __syncthreads();
  return r;
}

// ================= deep-pipelined 256-row MFMA GEMM: C = A * B^T =================
// (pair-mode, proven) — used for QKV / OProj / Down.
template <int BN, int WM, int WN, int RING, int UNROLL, class Epi>
__global__ __launch_bounds__(512, 2)
void gemm256(const bf16* __restrict__ A, int lda,
             const bf16* __restrict__ Bm, int ldb,
             int Kd, int GM, Epi epi) {
  constexpr int BM = 256;
  constexpr int FM = BM / WM / 16;
  constexpr int FN = BN / WN / 16;
  constexpr int ACALLS = 2;
  constexpr int BCALLS = BN / 128;
  constexpr int L = ACALLS + BCALLS;
  constexpr int D = RING - 1;
  constexpr int SLOTA = BM * 64;
  constexpr int SLOTB = BN * 64;
  constexpr int SLOT = SLOTA + SLOTB;
  __shared__ __align__(16) char lds[RING * SLOT];

  const int tid = threadIdx.x;
  const int lane = tid & 63;
  const int wid = tid >> 6;
  const int l15 = lane & 15, lq = lane >> 4;
  const int wr = wid / WN, wc = wid % WN;

  const int nwg = gridDim.x;
  const int xcd = blockIdx.x & 7, loc = blockIdx.x >> 3;
  const int wg = xcd * (nwg >> 3) + loc;
  const int GN = nwg / GM;
  const int per = 8 * GN;
  const int g = wg / per, r = wg % per;
  const int bm = g * 8 + (r & 7);
  const int bn = r >> 3;

  const bf16* Abase = A + (int64_t)bm * BM * lda;
  const bf16* Bbase = Bm + (int64_t)bn * BN * ldb;

  const bf16* srcA[ACALLS];
  int dstA[ACALLS];
#pragma unroll
  for (int c2 = 0; c2 < ACALLS; ++c2) {
    const int chunk = c2 * 512 + tid;
    const int row = chunk >> 2, pc = chunk & 3;
    const int lc = pc ^ ((row >> 1) & 3);
    srcA[c2] = Abase + (int64_t)row * lda + lc * 8;
    dstA[c2] = chunk * 16;
  }
  const bf16* srcB[BCALLS];
  int dstB[BCALLS];
#pragma unroll
  for (int c2 = 0; c2 < BCALLS; ++c2) {
    const int chunk = c2 * 512 + tid;
    const int row = chunk >> 2, pc = chunk & 3;
    const int lc = pc ^ ((row >> 1) & 3);
    srcB[c2] = Bbase + (int64_t)row * ldb + lc * 8;
    dstB[c2] = chunk * 16;
  }

  int offA[FM], offB[FN];
#pragma unroll
  for (int m = 0; m < FM; ++m) {
    const int row = wr * (BM / WM) + m * 16 + l15;
    offA[m] = row * 64 + (lq ^ ((row >> 1) & 3)) * 16;
  }
#pragma unroll
  for (int n = 0; n < FN; ++n) {
    const int row = wc * (BN / WN) + n * 16 + l15;
    offB[n] = SLOTA + row * 64 + (lq ^ ((row >> 1) & 3)) * 16;
  }

  const int KT = Kd >> 5;
  auto stage = [&](int t) {
    char* sb = lds + (size_t)(t % RING) * SLOT;
#pragma unroll
    for (int c2 = 0; c2 < ACALLS; ++c2)
      load_lds16(srcA[c2] + t * 32, sb + dstA[c2]);
#pragma unroll
    for (int c2 = 0; c2 < BCALLS; ++c2)
      load_lds16(srcB[c2] + t * 32, sb + SLOTA + dstB[c2]);
  };
  auto compute = [&](int t, f32x4 (&acc)[FM][FN]) {
    const char* sb = lds + (size_t)(t % RING) * SLOT;
    bf16x8 av[FM], bv[FN];
#pragma unroll
    for (int m = 0; m < FM; ++m) av[m] = *(const bf16x8*)(sb + offA[m]);
#pragma unroll
    for (int n = 0; n < FN; ++n) bv[n] = *(const bf16x8*)(sb + offB[n]);
    __builtin_amdgcn_s_setprio(1);
#pragma unroll
    for (int m = 0; m < FM; ++m)
#pragma unroll
      for (int n = 0; n < FN; ++n)
        acc[m][n] = __builtin_amdgcn_mfma_f32_16x16x32_bf16(av[m], bv[n], acc[m][n], 0, 0, 0);
    __builtin_amdgcn_s_setprio(0);
  };

  f32x4 acc[FM][FN] = {};

  if constexpr (UNROLL == 1) {
#pragma unroll
    for (int i = 0; i < D; ++i) stage(i);
    waitcnt_vm<(D - 1) * L>();
    __builtin_amdgcn_s_barrier();
    __builtin_amdgcn_sched_barrier(0);
    for (int t = 0; t < KT - D; ++t) {
      stage(t + D);
      compute(t, acc);
      waitcnt_vm<(D - 1) * L>();
      __builtin_amdgcn_s_barrier();
      __builtin_amdgcn_sched_barrier(0);
    }
    waitcnt_vm<0>();
    __builtin_amdgcn_s_barrier();
    for (int t = KT - D; t < KT; ++t) compute(t, acc);
  } else {
    static_assert(RING == 5 && UNROLL == 2, "pair mode is RING=5");
#pragma unroll
    for (int i = 0; i < 3; ++i) stage(i);
    waitcnt_vm<L>();
    __builtin_amdgcn_s_barrier();
    __builtin_amdgcn_sched_barrier(0);
    int t = 0;
    for (; t <= KT - 6; t += 2) {
      stage(t + 3);
      stage(t + 4);
      compute(t, acc);
      compute(t + 1, acc);
      waitcnt_vm<L>();
      __builtin_amdgcn_s_barrier();
      __builtin_amdgcn_sched_barrier(0);
    }
    stage(KT - 1);
    waitcnt_vm<0>();
    __builtin_amdgcn_s_barrier();
    compute(KT - 4, acc);
    compute(KT - 3, acc);
    compute(KT - 2, acc);
    compute(KT - 1, acc);
  }

#pragma unroll
  for (int m = 0; m < FM; ++m) {
    const int r0 = bm * BM + wr * (BM / WM) + m * 16 + lq * 4;
#pragma unroll
    for (int n = 0; n < FN; ++n) {
      const int c1 = bn * BN + wc * (BN / WN) + n * 16 + l15;
#pragma unroll
      for (int j = 0; j < 4; ++j) epi(r0 + j, c1, acc[m][n][j]);
    }
  }
}

// ========== gateup9: 2-blocks/CU fused gate+up GEMM (round 16) ==========
// Occupancy experiment: BM=256 x BN'=128 (interleaved B' -> 64 act cols), BK=32,
// acc[8][2] = 64 regs -> with launch_bounds(512,4) two blocks/CU (16 waves/CU) to
// hide barrier skew (gateup8 at 1 blk/CU plateaued at 46% MfmaUtil).
// Waves 2x4: wave = 128 A-rows x 32 B'-rows (= 1 G-group + 1 U-group, same 16 cols).
// LDS: 2 bufs x 6 quarters (A:4, B:2) x 4KB = 48 KB. 2 phases per K-tile:
//   p0: ldB + ldA(half0) | stage B(t+1), A02(t+1) | barrier | 8 MFMA | vmcnt(2) | barrier
//   p1: ldA(half1)       | stage A13(t+1)         | barrier | 8 MFMA | vmcnt(1) | barrier
// vmcnt ledger (1 load/thread per stage-pair; pairs in order B, A02, A13):
//   end-p0: outstanding [A13(t), B(t+1), A02(t+1)] -> vmcnt(2) retires A13(t) before
//           p1 reads it; TAIL (t=KT-1, nothing staged): vmcnt(0).
//   end-p1: outstanding [B(t+1), A02(t+1), A13(t+1)] -> vmcnt(1) retires B,A02 before
//           (t+1)-p0. Prologue: stage B(0),A02(0),A13(0); vmcnt(1); barrier.
// Swizzle: chunk ^= (row>>1)&3 both sides (2-way max = free).
__global__ __launch_bounds__(512, 4)
void gemm_gateup9(const bf16* __restrict__ A, const bf16* __restrict__ Bgu,
                  bf16* __restrict__ act) {
  constexpr int QSZ = 64 * 64;  // quarter: 64 rows x 64 B = 4 KB
  __shared__ __align__(16) char lds[2 * 6 * QSZ];  // 48 KB

  const int tid = threadIdx.x, lane = tid & 63;
  const int wid = tid >> 6;
  const int l15 = lane & 15, lq = lane >> 4;
  const int wr = wid >> 2, wc = wid & 3;  // 2 x 4 wave grid

  // grouped-XCD mapping (nwg = 2048, GM = 16, bm 8-fastest)
  const int nwg = gridDim.x;
  const int xcd = blockIdx.x & 7, loc = blockIdx.x >> 3;
  const int wg = xcd * (nwg >> 3) + loc;
  const int GM = 16, GN = nwg / GM;
  const int per = 8 * GN;
  const int g = wg / per, r = wg % per;
  const int bm = g * 8 + (r & 7);
  const int bn = r >> 3;  // 0..127

  const bf16* Abase = A + (int64_t)bm * 256 * cD;
  const bf16* Bbase = Bgu + (int64_t)bn * 128 * cD;

  // stage-pair thread mapping: pair = 2 quarters = 8 KB = 512 x 16B chunks
  const int sub = tid >> 8, cc = tid & 255;
  const int srow = cc >> 2, spc = cc & 3;
  const int slc = spc ^ ((srow >> 1) & 3);  // pre-swizzled global k-chunk
  // pair 0 = B quarters {0,1} -> slots {4,5}; pair 1 = A {0,2}; pair 2 = A {1,3}
  const bf16* psrc[3];
  int pdst[3];
  {
    const int qB = sub;          // B quarter
    psrc[0] = Bbase + (int64_t)(qB * 64 + srow) * cD + slc * 8;
    pdst[0] = (4 + qB) * QSZ + cc * 16;
    const int qA0 = sub * 2;     // A quarters 0,2
    psrc[1] = Abase + (int64_t)(qA0 * 64 + srow) * cD + slc * 8;
    pdst[1] = qA0 * QSZ + cc * 16;
    const int qA1 = 1 + sub * 2; // A quarters 1,3
    psrc[2] = Abase + (int64_t)(qA1 * 64 + srow) * cD + slc * 8;
    pdst[2] = qA1 * QSZ + cc * 16;
  }
  auto stageP = [&](int buf, int p, int kt) {
    load_lds16(psrc[p] + kt * 32, lds + (size_t)buf * 6 * QSZ + pdst[p]);
  };

  f32x4 acc[8][2] = {};
  bf16x8 af[4], bfr[2];

  auto ldA = [&](int buf, int half) {
    const char* qb = lds + (size_t)(buf * 6 + wr * 2 + half) * QSZ;
#pragma unroll
    for (int mq = 0; mq < 4; ++mq) {
      const int rr = mq * 16 + l15;
      af[mq] = *(const bf16x8*)(qb + rr * 64 + ((lq ^ ((rr >> 1) & 3)) * 16));
    }
  };
  auto ldB = [&](int buf) {
    const char* qb = lds + (size_t)(buf * 6 + 4 + (wc >> 1)) * QSZ;
#pragma unroll
    for (int nq = 0; nq < 2; ++nq) {
      const int rr = (wc & 1) * 32 + nq * 16 + l15;
      bfr[nq] = *(const bf16x8*)(qb + rr * 64 + ((lq ^ ((rr >> 1) & 3)) * 16));
    }
  };
  auto mfma8 = [&](int half) {
    __builtin_amdgcn_s_setprio(1);
#pragma unroll
    for (int mq = 0; mq < 4; ++mq)
#pragma unroll
      for (int nq = 0; nq < 2; ++nq)
        acc[half * 4 + mq][nq] = __builtin_amdgcn_mfma_f32_16x16x32_bf16(
            af[mq], bfr[nq], acc[half * 4 + mq][nq], 0, 0, 0);
    __builtin_amdgcn_s_setprio(0);
  };

  const int KT = cD >> 5;  // 64 K-tiles of 32

  // prologue: tile 0 pairs in retirement order
  stageP(0, 0, 0);  // B(0)
  stageP(0, 1, 0);  // A02(0)
  stageP(0, 2, 0);  // A13(0)
  waitcnt_vm<1>();
  __builtin_amdgcn_s_barrier();

  for (int t = 0; t < KT; ++t) {
    const int buf = t & 1, nb = buf ^ 1;
    const bool more = (t + 1 < KT);
    // phase 0: A half 0 x B
    ldB(buf);
    ldA(buf, 0);
    if (more) { stageP(nb, 0, t + 1); stageP(nb, 1, t + 1); }
    __builtin_amdgcn_s_barrier();
    mfma8(0);
    if (more) waitcnt_vm<2>();
    else      waitcnt_vm<0>();  // tail: retire A13(KT-1)
    __builtin_amdgcn_s_barrier();
    // phase 1: A half 1 x B (bfr still live)
    ldA(buf, 1);
    if (more) stageP(nb, 2, t + 1);
    __builtin_amdgcn_s_barrier();
    mfma8(1);
    if (more) waitcnt_vm<1>();
    __builtin_amdgcn_s_barrier();
  }

  // epilogue: acc[m][0] = G, acc[m][1] = U (same cols), silu-fuse, store
#pragma unroll
  for (int m = 0; m < 8; ++m) {
    const int row = bm * 256 + wr * 128 + m * 16 + lq * 4;
    const int col = bn * 64 + wc * 16 + l15;
#pragma unroll
    for (int j = 0; j < 4; ++j) {
      float gv = acc[m][0][j];
      float s = gv / (1.f + __expf(-gv));
      act[(int64_t)(row + j) * cFF + col] = (bf16)(s * acc[m][1][j]);
    }
  }
}

// ---------------- epilogues ----------------
struct EpiQKV {
  bf16* out; const float* bias;
  __device__ void operator()(int r, int c, float v) const {
    out[(int64_t)r * QKVW + c] = (bf16)(v + bias[c]);
  }
};
struct EpiOProj {
  float* x; const float* hidden; const int* topk;
  __device__ void operator()(int r, int c, float v) const {
    int b = r >> 10;
    int t = topk[r];
    x[(int64_t)r * cD + c] = v + hidden[((int64_t)b * cT + t) * cD + c];
  }
};
struct EpiDown {  // x2 = x + acc; upd = sel + (x2-sel)*gate; scatter to d_out
  float* out; const float* x; const float* hidden; const int* topk; const float* gating;
  __device__ void operator()(int r, int c, float v) const {
    int b = r >> 10;
    int t = topk[r];
    float x2 = v + x[(int64_t)r * cD + c];
    int64_t ho = ((int64_t)b * cT + t) * cD + c;
    float sel = hidden[ho];
    out[ho] = sel + (x2 - sel) * gating[r];
  }
};

// ================= fused flash attention (XCD-chunked remap) =================
__global__ __launch_bounds__(256, 2) void flash_attn(const bf16* __restrict__ qkv,
                                                     const bf16* __restrict__ vt,
                                                     bf16* __restrict__ outb) {
  constexpr int QB = 64, KVB = 128;
  __shared__ __align__(16) char lds[81920];
  char* sK = lds;            // 32 KB (also Q staging)
  char* sP = lds + 32768;    // 16 KB
  char* sV = lds + 49152;    // 32 KB

  const int xcdid = blockIdx.x & 7, locid = blockIdx.x >> 3;
  const int wg = xcdid * 128 + locid;
  const int qt = wg & 15, h = (wg >> 4) & 15, b = wg >> 8;
  const int kvh = h >> 2;
  const int qlo = qt * QB;
  const int tid = threadIdx.x, lane = tid & 63, wid = tid >> 6;
  const int l15 = lane & 15, lq = lane >> 4;
  const int wid16 = wid * 16;

  const bf16* qbase = qkv + (int64_t)(b * cK + qlo) * QKVW + h * cHD;
  const bf16* kbase = qkv + (int64_t)(b * cK) * QKVW + cH * cHD + kvh * cHD;
  const bf16* vtbase = vt + (int64_t)(b * cKVH + kvh) * cHD * cK;

#pragma unroll
  for (int c2 = 0; c2 < 4; ++c2) {
    int chunk = c2 * 256 + tid;
    int row = chunk >> 4, c16 = chunk & 15;
    load_lds16(qbase + (int64_t)row * QKVW + (c16 ^ (row & 15)) * 8, sK + chunk * 16);
  }
  __syncthreads();
  bf16x8 qf[4];
  {
    const int row = wid16 + l15;
#pragma unroll
    for (int kt = 0; kt < 4; ++kt)
      qf[kt] = *(const bf16x8*)(sK + row * 256 + (((kt * 4 + lq) ^ (row & 15)) * 16));
  }
  __syncthreads();

  f32x4 oacc[8] = {};
  float m_run[4], l_run[4];
#pragma unroll
  for (int j = 0; j < 4; ++j) { m_run[j] = -3.0e38f; l_run[j] = 0.f; }

  const int jmax = (qlo + QB - 1) >> 7;
  const float sl2e = 0.08838834764831845f * 1.44269504088896f;

  for (int jj = 0; jj <= jmax; ++jj) {
#pragma unroll
    for (int c2 = 0; c2 < 8; ++c2) {
      int chunk = c2 * 256 + tid;
      int row = chunk >> 4, c16 = chunk & 15;
      int cs = (c16 ^ (row & 15)) * 8;
      load_lds16(kbase + (int64_t)(jj * KVB + row) * QKVW + cs, sK + chunk * 16);
      load_lds16(vtbase + (int64_t)row * cK + jj * KVB + cs, sV + chunk * 16);
    }
    __syncthreads();

    f32x4 sacc[8] = {};
#pragma unroll
    for (int kt = 0; kt < 4; ++kt) {
      bf16x8 bv[8];
#pragma unroll
      for (int n = 0; n < 8; ++n) {
        int rk = n * 16 + l15;
        bv[n] = *(const bf16x8*)(sK + rk * 256 + (((kt * 4 + lq) ^ (rk & 15)) * 16));
      }
#pragma unroll
      for (int n = 0; n < 8; ++n)
        sacc[n] = __builtin_amdgcn_mfma_f32_16x16x32_bf16(qf[kt], bv[n], sacc[n], 0, 0, 0);
    }

    if (jj == jmax) {
#pragma unroll
      for (int n = 0; n < 8; ++n)
#pragma unroll
        for (int j = 0; j < 4; ++j) {
          int qrow = qlo + wid16 + lq * 4 + j;
          int kcol = jj * KVB + n * 16 + l15;
          if (kcol > qrow) sacc[n][j] = -3.0e38f;
        }
    }

#pragma unroll
    for (int j = 0; j < 4; ++j) {
      float mx = sacc[0][j];
#pragma unroll
      for (int n = 1; n < 8; ++n) mx = fmaxf(mx, sacc[n][j]);
#pragma unroll
      for (int off = 1; off < 16; off <<= 1) mx = fmaxf(mx, __shfl_xor(mx, off, 64));
      float mnew = fmaxf(m_run[j], mx);
      float corr = exp2f((m_run[j] - mnew) * sl2e);
      m_run[j] = mnew;
      float ps = 0.f;
#pragma unroll
      for (int n = 0; n < 8; ++n) {
        float p = exp2f((sacc[n][j] - mnew) * sl2e);
        sacc[n][j] = p;
        ps += p;
      }
#pragma unroll
      for (int off = 1; off < 16; off <<= 1) ps += __shfl_xor(ps, off, 64);
      l_run[j] = l_run[j] * corr + ps;
#pragma unroll
      for (int n = 0; n < 8; ++n) oacc[n][j] *= corr;
    }

#pragma unroll
    for (int n = 0; n < 8; ++n)
#pragma unroll
      for (int j = 0; j < 4; ++j) {
        int row = wid16 + lq * 4 + j;
        int col = n * 16 + l15;
        int c16 = (col >> 3) ^ (row & 15);
        *(bf16*)(sP + row * 256 + c16 * 16 + (col & 7) * 2) = (bf16)sacc[n][j];
      }
    __syncthreads();

#pragma unroll
    for (int kt = 0; kt < 4; ++kt) {
      const int prow = wid16 + l15;
      bf16x8 av = *(const bf16x8*)(sP + prow * 256 + (((kt * 4 + lq) ^ (prow & 15)) * 16));
      bf16x8 bv[8];
#pragma unroll
      for (int n = 0; n < 8; ++n) {
        int rd = n * 16 + l15;
        bv[n] = *(const bf16x8*)(sV + rd * 256 + (((kt * 4 + lq) ^ (rd & 15)) * 16));
      }
#pragma unroll
      for (int n = 0; n < 8; ++n)
        oacc[n] = __builtin_amdgcn_mfma_f32_16x16x32_bf16(av, bv[n], oacc[n], 0, 0, 0);
    }
    __syncthreads();
  }

#pragma unroll
  for (int j = 0; j < 4; ++j) {
    int row = qlo + wid16 + lq * 4 + j;
    float inv = 1.f / l_run[j];
#pragma unroll
    for (int n = 0; n < 8; ++n) {
      int col = h * cHD + n * 16 + l15;
      outb[((int64_t)b * cK + row) * cD + col] = (bf16)(oacc[n][j] * inv);
    }
  }
}

// ---------------- elementwise / staging kernels ----------------
__global__ void copy_skip(const float4* __restrict__ s, float4* __restrict__ d,
                          const unsigned char* __restrict__ flags, int64_t n) {
  int64_t i = (int64_t)blockIdx.x * blockDim.x + threadIdx.x;
  const int64_t st = (int64_t)gridDim.x * blockDim.x;
  for (; i < n; i += st) {
    int row = (int)(i >> 9);
    if (!flags[row]) d[i] = s[i];
  }
}

__global__ void build_flags(const int* __restrict__ topk, unsigned char* __restrict__ flags) {
  int r = blockIdx.x * 256 + threadIdx.x;
  if (r < cM) flags[(r >> 10) * cT + topk[r]] = 1;
}

// fp32 (R,C) -> bf16 (C,R) with column offset into a concat buffer
__global__ void wconv(const float* __restrict__ src, bf16* __restrict__ dst,
                      int R, int C, int coff, int ldd) {
  __shared__ float t[32][33];
  const int c0 = blockIdx.x * 32, r0 = blockIdx.y * 32;
  for (int rr = threadIdx.y; rr < 32; rr += 8)
    t[rr][threadIdx.x] = src[(int64_t)(r0 + rr) * C + c0 + threadIdx.x];
  __syncthreads();
  for (int rr = threadIdx.y; rr < 32; rr += 8)
    dst[(int64_t)(c0 + rr + coff) * ldd + r0 + threadIdx.x] = (bf16)t[threadIdx.x][rr];
}

// gate/up fp32 (cD, cFF) -> B' bf16 (2*cFF, cD), 16-rows-G / 16-rows-U interleaved:
// gate col c -> B'-row ((c&~15)<<1)|(c&15); up col c -> +16.
__global__ void wconv_gu(const float* __restrict__ srcG, const float* __restrict__ srcU,
                         bf16* __restrict__ dst) {
  __shared__ float t[32][33];
  const float* src = blockIdx.z ? srcU : srcG;
  const int c0 = blockIdx.x * 32, r0 = blockIdx.y * 32;
  for (int rr = threadIdx.y; rr < 32; rr += 8)
    t[rr][threadIdx.x] = src[(int64_t)(r0 + rr) * cFF + c0 + threadIdx.x];
  __syncthreads();
  for (int rr = threadIdx.y; rr < 32; rr += 8) {
    int c = c0 + rr;
    int dr = ((c & ~15) << 1) | (blockIdx.z ? 16 : 0) | (c & 15);
    dst[(int64_t)dr * cD + r0 + threadIdx.x] = (bf16)t[threadIdx.x][rr];
  }
}

__global__ void biascat(const float* __restrict__ bq, const float* __restrict__ bk,
                        const float* __restrict__ bv, float* __restrict__ o) {
  int i = blockIdx.x * 256 + threadIdx.x;
  if (i < QKVW) o[i] = (i < 2048) ? bq[i] : (i < 2560 ? bk[i - 2048] : bv[i - 2560]);
}

__global__ void rmsnorm_rows(const float* __restrict__ base, const int* __restrict__ topk,
                             const float* __restrict__ w, bf16* __restrict__ out) {
  const int r = blockIdx.x;
  const float* src;
  if (topk) {
    int t = topk[r];
    src = base + ((int64_t)(r >> 10) * cT + t) * cD;
  } else {
    src = base + (int64_t)r * cD;
  }
  const int tid = threadIdx.x;
  const float4* s4 = (const float4*)src;
  float4 a = s4[tid * 2], b = s4[tid * 2 + 1];
  float ss = a.x * a.x + a.y * a.y + a.z * a.z + a.w * a.w +
             b.x * b.x + b.y * b.y + b.z * b.z + b.w * b.w;
  float tot = blk_reduce<0>(ss);
  float sc = rsqrtf(tot * (1.f / cD) + 1e-6f);
  bf16* o = out + (int64_t)r * cD;
  const int d0 = tid * 8;
  o[d0 + 0] = (bf16)(a.x * sc * w[d0 + 0]);
  o[d0 + 1] = (bf16)(a.y * sc * w[d0 + 1]);
  o[d0 + 2] = (bf16)(a.z * sc * w[d0 + 2]);
  o[d0 + 3] = (bf16)(a.w * sc * w[d0 + 3]);
  o[d0 + 4] = (bf16)(b.x * sc * w[d0 + 4]);
  o[d0 + 5] = (bf16)(b.y * sc * w[d0 + 5]);
  o[d0 + 6] = (bf16)(b.z * sc * w[d0 + 6]);
  o[d0 + 7] = (bf16)(b.w * sc * w[d0 + 7]);
}

__global__ void rope_kernel(bf16* __restrict__ qkv, const float* __restrict__ cosb,
                            const float* __restrict__ sinb, const int* __restrict__ topk) {
  const int r = blockIdx.x;
  const int b = r >> 10;
  const int t = topk[r];
  const float* cr = cosb + ((int64_t)b * cT + t) * cHD;
  const float* sr = sinb + ((int64_t)b * cT + t) * cHD;
  bf16* rowq = qkv + (int64_t)r * QKVW;
  for (int p = threadIdx.x; p < (cH + cKVH) * 64; p += 256) {
    int hh = p >> 6, d = p & 63;
    bf16* base = (hh < cH) ? (rowq + hh * cHD) : (rowq + cH * cHD + (hh - cH) * cHD);
    float x1 = (float)base[d], x2 = (float)base[d + 64];
    float c1 = cr[d], s1 = sr[d], c2 = cr[d + 64], s2 = sr[d + 64];
    base[d] = (bf16)(x1 * c1 - x2 * s1);
    base[d + 64] = (bf16)(x2 * c2 + x1 * s2);
  }
}

__global__ void vtrans(const bf16* __restrict__ qkv, bf16* __restrict__ Vt) {
  __shared__ bf16 t[32][33];
  const int bz = blockIdx.z, b = bz >> 2, kv = bz & 3;
  const int k0 = blockIdx.x * 32, d0 = blockIdx.y * 32;
  for (int rr = threadIdx.y; rr < 32; rr += 8)
    t[rr][threadIdx.x] =
        qkv[(int64_t)(b * cK + k0 + rr) * QKVW + cH * cHD + cKVH * cHD + kv * cHD + d0 + threadIdx.x];
  __syncthreads();
  for (int rr = threadIdx.y; rr < 32; rr += 8)
    Vt[((int64_t)(b * cKVH + kv) * cHD + d0 + rr) * cK + k0 + threadIdx.x] = t[threadIdx.x][rr];
}

}  // namespace

extern "C" void kernel_launch(void* const* d_in, const int* in_sizes, int n_in,
                              void* d_out, int out_size, void* d_ws, size_t ws_size,
                              hipStream_t stream) {
  const float* hidden = (const float*)d_in[0];
  const int* topk = (const int*)d_in[1];
  const float* gating = (const float*)d_in[2];
  const float* cosb = (const float*)d_in[3];
  const float* sinb = (const float*)d_in[4];
  const float* Wq = (const float*)d_in[5];
  const float* bq = (const float*)d_in[6];
  const float* Wk = (const float*)d_in[7];
  const float* bk = (const float*)d_in[8];
  const float* Wv = (const float*)d_in[9];
  const float* bv = (const float*)d_in[10];
  const float* Wo = (const float*)d_in[11];
  const float* wg = (const float*)d_in[12];
  const float* wu = (const float*)d_in[13];
  const float* wd = (const float*)d_in[14];
  const float* ln1 = (const float*)d_in[15];
  const float* ln2 = (const float*)d_in[16];
  float* out = (float*)d_out;
  (void)in_sizes; (void)n_in; (void)out_size; (void)ws_size;

  char* ws = (char*)d_ws;
  size_t off = 0;
  auto alloc = [&](size_t bytes) {
    char* p = ws + off;
    off += (bytes + 255) & ~(size_t)255;
    return p;
  };
  bf16* wt_qkv = (bf16*)alloc((size_t)QKVW * cD * 2);
  bf16* wt_o = (bf16*)alloc((size_t)cD * cD * 2);
  bf16* wt_gu = (bf16*)alloc((size_t)2 * cFF * cD * 2);
  bf16* wt_d = (bf16*)alloc((size_t)cD * cFF * 2);
  float* bias_cat = (float*)alloc((size_t)QKVW * 4);
  bf16* hbuf = (bf16*)alloc((size_t)cM * cD * 2);
  bf16* qkv = (bf16*)alloc((size_t)cM * QKVW * 2);
  bf16* vt = (bf16*)alloc((size_t)cB * cKVH * cHD * cK * 2);
  bf16* attnout = (bf16*)alloc((size_t)cM * cD * 2);
  float* xbuf = (float*)alloc((size_t)cM * cD * 4);
  bf16* actbuf = (bf16*)alloc((size_t)cM * cFF * 2);
  unsigned char* flags = (unsigned char*)alloc((size_t)cB * cT);

  // flags = selected-row mask; copy only unselected rows (EpiDown writes selected)
  (void)hipMemsetAsync(flags, 0, (size_t)cB * cT, stream);
  build_flags<<<cM / 256, 256, 0, stream>>>(topk, flags);
  copy_skip<<<2048, 256, 0, stream>>>((const float4*)hidden, (float4*)out, flags,
                                      (int64_t)cB * cT * cD / 4);

  const dim3 tb(32, 8);
  wconv<<<dim3(cD / 32, cD / 32), tb, 0, stream>>>(Wq, wt_qkv, cD, cD, 0, cD);
  wconv<<<dim3(512 / 32, cD / 32), tb, 0, stream>>>(Wk, wt_qkv, cD, 512, 2048, cD);
  wconv<<<dim3(512 / 32, cD / 32), tb, 0, stream>>>(Wv, wt_qkv, cD, 512, 2560, cD);
  wconv<<<dim3(cD / 32, cD / 32), tb, 0, stream>>>(Wo, wt_o, cD, cD, 0, cD);
  wconv_gu<<<dim3(cFF / 32, cD / 32, 2), tb, 0, stream>>>(wg, wu, wt_gu);
  wconv<<<dim3(cD / 32, cFF / 32), tb, 0, stream>>>(wd, wt_d, cFF, cD, 0, cFF);
  biascat<<<(QKVW + 255) / 256, 256, 0, stream>>>(bq, bk, bv, bias_cat);

  // gather + rmsnorm1
  rmsnorm_rows<<<cM, 256, 0, stream>>>(hidden, topk, ln1, hbuf);
  // qkv projection (+bias)   [pair-mode pipeline]
  gemm256<256, 2, 4, 5, 2, EpiQKV><<<16 * (QKVW / 256), 512, 0, stream>>>(
      hbuf, cD, wt_qkv, cD, cD, 16, EpiQKV{qkv, bias_cat});
  rope_kernel<<<cM, 256, 0, stream>>>(qkv, cosb, sinb, topk);
  vtrans<<<dim3(cK / 32, cHD / 32, cB * cKVH), tb, 0, stream>>>(qkv, vt);

  // fused flash attention (1D grid, XCD-chunked remap for KV L2 locality)
  flash_attn<<<1024, 256, 0, stream>>>(qkv, vt, attnout);

  // o-proj + gathered residual -> x (fp32)   [pair-mode pipeline]
  gemm256<128, 4, 2, 5, 2, EpiOProj><<<16 * (cD / 128), 512, 0, stream>>>(
      attnout, cD, wt_o, cD, cD, 16, EpiOProj{xbuf, hidden, topk});
  // rmsnorm2
  rmsnorm_rows<<<cM, 256, 0, stream>>>(xbuf, nullptr, ln2, hbuf);
  // fused gate+up -> act = silu(gate)*up   [2-blocks/CU BK=32 pipeline]
  gemm_gateup9<<<16 * (2 * cFF / 128), 512, 0, stream>>>(hbuf, wt_gu, actbuf);
  // down + residual + gating + scatter into d_out   [pair-mode pipeline]
  gemm256<128, 4, 2, 5, 2, EpiDown><<<16 * (cD / 128), 512, 0, stream>>>(
      actbuf, cFF, wt_d, cFF, cFF, 16, EpiDown{out, xbuf, hidden, topk, gating});
}

// Round 17
// 835.771 us; speedup vs baseline: 1.0625x; 1.0625x over previous
//
#include <hip/hip_runtime.h>
#include <stdint.h>

typedef __bf16 bf16;
typedef __attribute__((ext_vector_type(8))) __bf16 bf16x8;
typedef __attribute__((ext_vector_type(4))) float f32x4;

namespace {

constexpr int cB = 4, cT = 4096, cD = 2048, cK = 1024, cH = 16, cKVH = 4, cHD = 128, cFF = 8192;
constexpr int cM = cB * cK;                 // 4096 gathered rows
constexpr int QKVW = cH * cHD + 2 * cKVH * cHD; // 3072

__device__ __forceinline__ void load_lds16(const void* g, void* l) {
  __builtin_amdgcn_global_load_lds((const __attribute__((address_space(1))) void*)g,
                                   (__attribute__((address_space(3))) void*)l, 16, 0, 0);
}

template <int N>
__device__ __forceinline__ void waitcnt_vm() {
  if constexpr (N == 0) asm volatile("s_waitcnt vmcnt(0)" ::: "memory");
  else if constexpr (N == 2) asm volatile("s_waitcnt vmcnt(2)" ::: "memory");
  else if constexpr (N == 3) asm volatile("s_waitcnt vmcnt(3)" ::: "memory");
  else if constexpr (N == 4) asm volatile("s_waitcnt vmcnt(4)" ::: "memory");
  else if constexpr (N == 6) asm volatile("s_waitcnt vmcnt(6)" ::: "memory");
  else if constexpr (N == 8) asm volatile("s_waitcnt vmcnt(8)" ::: "memory");
  else static_assert(N == 0, "unsupported vmcnt literal");
}

// ---------------- block reduce (256 threads = 4 waves) ----------------
template <int OP>  // 0 = sum, 1 = max
__device__ __forceinline__ float blk_reduce(float v) {
  __shared__ float sm[5];
  const int tid = threadIdx.x, lane = tid & 63, wid = tid >> 6;
#pragma unroll
  for (int o = 32; o; o >>= 1) {
    float o2 = __shfl_down(v, o, 64);
    v = OP ? fmaxf(v, o2) : v + o2;
  }
  if (lane == 0) sm[wid] = v;
  __syncthreads();
  if (tid == 0) {
    float r = sm[0];
#pragma unroll
    for (int i = 1; i < 4; ++i) r = OP ? fmaxf(r, sm[i]) : r + sm[i];
    sm[4] = r;
  }
  __syncthreads();
  float r = sm[4];
  __syncthreads();
  return r;
}

// ================= deep-pipelined 256-row MFMA GEMM: C = A * B^T =================
// (pair-mode, proven) — used for QKV / OProj / Down.
template <int BN, int WM, int WN, int RING, int UNROLL, class Epi>
__global__ __launch_bounds__(512, 2)
void gemm256(const bf16* __restrict__ A, int lda,
             const bf16* __restrict__ Bm, int ldb,
             int Kd, int GM, Epi epi) {
  constexpr int BM = 256;
  constexpr int FM = BM / WM / 16;
  constexpr int FN = BN / WN / 16;
  constexpr int ACALLS = 2;
  constexpr int BCALLS = BN / 128;
  constexpr int L = ACALLS + BCALLS;
  constexpr int D = RING - 1;
  constexpr int SLOTA = BM * 64;
  constexpr int SLOTB = BN * 64;
  constexpr int SLOT = SLOTA + SLOTB;
  __shared__ __align__(16) char lds[RING * SLOT];

  const int tid = threadIdx.x;
  const int lane = tid & 63;
  const int wid = tid >> 6;
  const int l15 = lane & 15, lq = lane >> 4;
  const int wr = wid / WN, wc = wid % WN;

  const int nwg = gridDim.x;
  const int xcd = blockIdx.x & 7, loc = blockIdx.x >> 3;
  const int wg = xcd * (nwg >> 3) + loc;
  const int GN = nwg / GM;
  const int per = 8 * GN;
  const int g = wg / per, r = wg % per;
  const int bm = g * 8 + (r & 7);
  const int bn = r >> 3;

  const bf16* Abase = A + (int64_t)bm * BM * lda;
  const bf16* Bbase = Bm + (int64_t)bn * BN * ldb;

  const bf16* srcA[ACALLS];
  int dstA[ACALLS];
#pragma unroll
  for (int c2 = 0; c2 < ACALLS; ++c2) {
    const int chunk = c2 * 512 + tid;
    const int row = chunk >> 2, pc = chunk & 3;
    const int lc = pc ^ ((row >> 1) & 3);
    srcA[c2] = Abase + (int64_t)row * lda + lc * 8;
    dstA[c2] = chunk * 16;
  }
  const bf16* srcB[BCALLS];
  int dstB[BCALLS];
#pragma unroll
  for (int c2 = 0; c2 < BCALLS; ++c2) {
    const int chunk = c2 * 512 + tid;
    const int row = chunk >> 2, pc = chunk & 3;
    const int lc = pc ^ ((row >> 1) & 3);
    srcB[c2] = Bbase + (int64_t)row * ldb + lc * 8;
    dstB[c2] = chunk * 16;
  }

  int offA[FM], offB[FN];
#pragma unroll
  for (int m = 0; m < FM; ++m) {
    const int row = wr * (BM / WM) + m * 16 + l15;
    offA[m] = row * 64 + (lq ^ ((row >> 1) & 3)) * 16;
  }
#pragma unroll
  for (int n = 0; n < FN; ++n) {
    const int row = wc * (BN / WN) + n * 16 + l15;
    offB[n] = SLOTA + row * 64 + (lq ^ ((row >> 1) & 3)) * 16;
  }

  const int KT = Kd >> 5;
  auto stage = [&](int t) {
    char* sb = lds + (size_t)(t % RING) * SLOT;
#pragma unroll
    for (int c2 = 0; c2 < ACALLS; ++c2)
      load_lds16(srcA[c2] + t * 32, sb + dstA[c2]);
#pragma unroll
    for (int c2 = 0; c2 < BCALLS; ++c2)
      load_lds16(srcB[c2] + t * 32, sb + SLOTA + dstB[c2]);
  };
  auto compute = [&](int t, f32x4 (&acc)[FM][FN]) {
    const char* sb = lds + (size_t)(t % RING) * SLOT;
    bf16x8 av[FM], bv[FN];
#pragma unroll
    for (int m = 0; m < FM; ++m) av[m] = *(const bf16x8*)(sb + offA[m]);
#pragma unroll
    for (int n = 0; n < FN; ++n) bv[n] = *(const bf16x8*)(sb + offB[n]);
    __builtin_amdgcn_s_setprio(1);
#pragma unroll
    for (int m = 0; m < FM; ++m)
#pragma unroll
      for (int n = 0; n < FN; ++n)
        acc[m][n] = __builtin_amdgcn_mfma_f32_16x16x32_bf16(av[m], bv[n], acc[m][n], 0, 0, 0);
    __builtin_amdgcn_s_setprio(0);
  };

  f32x4 acc[FM][FN] = {};

  if constexpr (UNROLL == 1) {
#pragma unroll
    for (int i = 0; i < D; ++i) stage(i);
    waitcnt_vm<(D - 1) * L>();
    __builtin_amdgcn_s_barrier();
    __builtin_amdgcn_sched_barrier(0);
    for (int t = 0; t < KT - D; ++t) {
      stage(t + D);
      compute(t, acc);
      waitcnt_vm<(D - 1) * L>();
      __builtin_amdgcn_s_barrier();
      __builtin_amdgcn_sched_barrier(0);
    }
    waitcnt_vm<0>();
    __builtin_amdgcn_s_barrier();
    for (int t = KT - D; t < KT; ++t) compute(t, acc);
  } else {
    static_assert(RING == 5 && UNROLL == 2, "pair mode is RING=5");
#pragma unroll
    for (int i = 0; i < 3; ++i) stage(i);
    waitcnt_vm<L>();
    __builtin_amdgcn_s_barrier();
    __builtin_amdgcn_sched_barrier(0);
    int t = 0;
    for (; t <= KT - 6; t += 2) {
      stage(t + 3);
      stage(t + 4);
      compute(t, acc);
      compute(t + 1, acc);
      waitcnt_vm<L>();
      __builtin_amdgcn_s_barrier();
      __builtin_amdgcn_sched_barrier(0);
    }
    stage(KT - 1);
    waitcnt_vm<0>();
    __builtin_amdgcn_s_barrier();
    compute(KT - 4, acc);
    compute(KT - 3, acc);
    compute(KT - 2, acc);
    compute(KT - 1, acc);
  }

#pragma unroll
  for (int m = 0; m < FM; ++m) {
    const int r0 = bm * BM + wr * (BM / WM) + m * 16 + lq * 4;
#pragma unroll
    for (int n = 0; n < FN; ++n) {
      const int c1 = bn * BN + wc * (BN / WN) + n * 16 + l15;
#pragma unroll
      for (int j = 0; j < 4; ++j) epi(r0 + j, c1, acc[m][n][j]);
    }
  }
}

// ========== 8-phase fused gate+up GEMM (m201 schedule port — session best) ==========
// B' = gate/up weights interleaved 16-rows-G / 16-rows-U (wconv_gu): exact 256x256
// single-B GEMM; silu pairing same-wave same-lane: silu(acc[m][2p]) * acc[m][2p+1].
// BK=64, double-buffered LDS (2 x 8 quarters x 8 KB = 128 KB), 4 phases/K-tile.
// vmcnt ledger: end-p1 vmcnt(4) (tail 0), end-p3 vmcnt(2); never 0 in-loop.
// Measured 267 us (vs 274 2-phase, 279 pair, 293/357 B-in-reg, 309 2-blk/CU).
__global__ __launch_bounds__(512, 2)
void gemm_gateup8(const bf16* __restrict__ A, const bf16* __restrict__ Bgu,
                  bf16* __restrict__ act) {
  constexpr int QSZ = 64 * 128;  // quarter: 64 rows x 128 B = 8 KB
  __shared__ __align__(16) char lds[2 * 8 * QSZ];  // 128 KB

  const int tid = threadIdx.x, lane = tid & 63;
  const int wid = tid >> 6;
  const int l15 = lane & 15, lq = lane >> 4;
  const int wr = wid >> 2, wc = wid & 3;  // 2 x 4 wave grid

  const int nwg = gridDim.x;
  const int xcd = blockIdx.x & 7, loc = blockIdx.x >> 3;
  const int wg = xcd * (nwg >> 3) + loc;
  const int GM = 16, GN = nwg / GM;
  const int per = 8 * GN;
  const int g = wg / per, r = wg % per;
  const int bm = g * 8 + (r & 7);
  const int bn = r >> 3;

  const bf16* Abase = A + (int64_t)bm * 256 * cD;
  const bf16* Bbase = Bgu + (int64_t)bn * 256 * cD;

  const int srow = tid >> 3, spc = tid & 7;
  const int slc = spc ^ (srow & 7);  // pre-swizzled global k-chunk
  const int sdst = tid * 16;
  const bf16* qsrc[8];
#pragma unroll
  for (int q = 0; q < 4; ++q) qsrc[q] = Abase + (int64_t)(q * 64 + srow) * cD + slc * 8;
#pragma unroll
  for (int q = 0; q < 4; ++q) qsrc[4 + q] = Bbase + (int64_t)(q * 64 + srow) * cD + slc * 8;

  auto stageQ = [&](int buf, int q, int kt) {
    load_lds16(qsrc[q] + kt * 64, lds + (size_t)(buf * 8 + q) * QSZ + sdst);
  };

  f32x4 acc[8][4] = {};
  bf16x8 af[4][2], bfr[2][2];

  auto ldA = [&](int buf, int qr) {
    const char* qb = lds + (size_t)(buf * 8 + wr * 2 + qr) * QSZ;
#pragma unroll
    for (int mq = 0; mq < 4; ++mq) {
      const int rr = mq * 16 + l15;
#pragma unroll
      for (int ks = 0; ks < 2; ++ks)
        af[mq][ks] = *(const bf16x8*)(qb + rr * 128 + (((ks * 4 + lq) ^ (rr & 7)) * 16));
    }
  };
  auto ldB = [&](int buf, int qc) {
    const char* qb = lds + (size_t)(buf * 8 + 4 + wc) * QSZ;
#pragma unroll
    for (int nq = 0; nq < 2; ++nq) {
      const int rr = qc * 32 + nq * 16 + l15;
#pragma unroll
      for (int ks = 0; ks < 2; ++ks)
        bfr[nq][ks] = *(const bf16x8*)(qb + rr * 128 + (((ks * 4 + lq) ^ (rr & 7)) * 16));
    }
  };
  auto mfma16 = [&](int qr, int qc) {
    __builtin_amdgcn_s_setprio(1);
#pragma unroll
    for (int ks = 0; ks < 2; ++ks)
#pragma unroll
      for (int mq = 0; mq < 4; ++mq)
#pragma unroll
        for (int nq = 0; nq < 2; ++nq)
          acc[qr * 4 + mq][qc * 2 + nq] = __builtin_amdgcn_mfma_f32_16x16x32_bf16(
              af[mq][ks], bfr[nq][ks], acc[qr * 4 + mq][qc * 2 + nq], 0, 0, 0);
    __builtin_amdgcn_s_setprio(0);
  };

  const int KT = cD >> 6;  // 32 K-tiles of 64

  stageQ(0, 4, 0); stageQ(0, 5, 0);
  stageQ(0, 6, 0); stageQ(0, 7, 0);
  stageQ(0, 0, 0); stageQ(0, 2, 0);
  stageQ(0, 1, 0); stageQ(0, 3, 0);
  waitcnt_vm<2>();
  __builtin_amdgcn_s_barrier();

  for (int t = 0; t < KT; ++t) {
    const int buf = t & 1, nb = buf ^ 1;
    const bool more = (t + 1 < KT);
    ldA(buf, 0);
    ldB(buf, 0);
    if (more) { stageQ(nb, 4, t + 1); stageQ(nb, 5, t + 1); }
    __builtin_amdgcn_s_barrier();
    mfma16(0, 0);
    __builtin_amdgcn_s_barrier();
    ldB(buf, 1);
    if (more) { stageQ(nb, 6, t + 1); stageQ(nb, 7, t + 1); }
    __builtin_amdgcn_s_barrier();
    mfma16(0, 1);
    if (more) waitcnt_vm<4>();
    else      waitcnt_vm<0>();
    __builtin_amdgcn_s_barrier();
    ldA(buf, 1);
    if (more) { stageQ(nb, 0, t + 1); stageQ(nb, 2, t + 1); }
    __builtin_amdgcn_s_barrier();
    mfma16(1, 1);
    __builtin_amdgcn_s_barrier();
    ldB(buf, 0);
    if (more) { stageQ(nb, 1, t + 1); stageQ(nb, 3, t + 1); }
    __builtin_amdgcn_s_barrier();
    mfma16(1, 0);
    if (more) waitcnt_vm<2>();
    __builtin_amdgcn_s_barrier();
  }

#pragma unroll
  for (int m = 0; m < 8; ++m) {
    const int row = bm * 256 + wr * 128 + (m >> 2) * 64 + (m & 3) * 16 + lq * 4;
#pragma unroll
    for (int p = 0; p < 2; ++p) {
      const int col = bn * 128 + wc * 32 + p * 16 + l15;
#pragma unroll
      for (int j = 0; j < 4; ++j) {
        float gv = acc[m][2 * p][j];
        float s = gv / (1.f + __expf(-gv));
        act[(int64_t)(row + j) * cFF + col] = (bf16)(s * acc[m][2 * p + 1][j]);
      }
    }
  }
}

// ---------------- epilogues ----------------
struct EpiQKV {
  bf16* out; const float* bias;
  __device__ void operator()(int r, int c, float v) const {
    out[(int64_t)r * QKVW + c] = (bf16)(v + bias[c]);
  }
};
struct EpiOProj {
  float* x; const float* hidden; const int* topk;
  __device__ void operator()(int r, int c, float v) const {
    int b = r >> 10;
    int t = topk[r];
    x[(int64_t)r * cD + c] = v + hidden[((int64_t)b * cT + t) * cD + c];
  }
};
struct EpiDown {  // x2 = x + acc; upd = sel + (x2-sel)*gate; scatter to d_out
  float* out; const float* x; const float* hidden; const int* topk; const float* gating;
  __device__ void operator()(int r, int c, float v) const {
    int b = r >> 10;
    int t = topk[r];
    float x2 = v + x[(int64_t)r * cD + c];
    int64_t ho = ((int64_t)b * cT + t) * cD + c;
    float sel = hidden[ho];
    out[ho] = sel + (x2 - sel) * gating[r];
  }
};

// ================= fused flash attention (XCD-chunked remap) =================
__global__ __launch_bounds__(256, 2) void flash_attn(const bf16* __restrict__ qkv,
                                                     const bf16* __restrict__ vt,
                                                     bf16* __restrict__ outb) {
  constexpr int QB = 64, KVB = 128;
  __shared__ __align__(16) char lds[81920];
  char* sK = lds;            // 32 KB (also Q staging)
  char* sP = lds + 32768;    // 16 KB
  char* sV = lds + 49152;    // 32 KB

  const int xcdid = blockIdx.x & 7, locid = blockIdx.x >> 3;
  const int wg = xcdid * 128 + locid;
  const int qt = wg & 15, h = (wg >> 4) & 15, b = wg >> 8;
  const int kvh = h >> 2;
  const int qlo = qt * QB;
  const int tid = threadIdx.x, lane = tid & 63, wid = tid >> 6;
  const int l15 = lane & 15, lq = lane >> 4;
  const int wid16 = wid * 16;

  const bf16* qbase = qkv + (int64_t)(b * cK + qlo) * QKVW + h * cHD;
  const bf16* kbase = qkv + (int64_t)(b * cK) * QKVW + cH * cHD + kvh * cHD;
  const bf16* vtbase = vt + (int64_t)(b * cKVH + kvh) * cHD * cK;

#pragma unroll
  for (int c2 = 0; c2 < 4; ++c2) {
    int chunk = c2 * 256 + tid;
    int row = chunk >> 4, c16 = chunk & 15;
    load_lds16(qbase + (int64_t)row * QKVW + (c16 ^ (row & 15)) * 8, sK + chunk * 16);
  }
  __syncthreads();
  bf16x8 qf[4];
  {
    const int row = wid16 + l15;
#pragma unroll
    for (int kt = 0; kt < 4; ++kt)
      qf[kt] = *(const bf16x8*)(sK + row * 256 + (((kt * 4 + lq) ^ (row & 15)) * 16));
  }
  __syncthreads();

  f32x4 oacc[8] = {};
  float m_run[4], l_run[4];
#pragma unroll
  for (int j = 0; j < 4; ++j) { m_run[j] = -3.0e38f; l_run[j] = 0.f; }

  const int jmax = (qlo + QB - 1) >> 7;
  const float sl2e = 0.08838834764831845f * 1.44269504088896f;

  for (int jj = 0; jj <= jmax; ++jj) {
#pragma unroll
    for (int c2 = 0; c2 < 8; ++c2) {
      int chunk = c2 * 256 + tid;
      int row = chunk >> 4, c16 = chunk & 15;
      int cs = (c16 ^ (row & 15)) * 8;
      load_lds16(kbase + (int64_t)(jj * KVB + row) * QKVW + cs, sK + chunk * 16);
      load_lds16(vtbase + (int64_t)row * cK + jj * KVB + cs, sV + chunk * 16);
    }
    __syncthreads();

    f32x4 sacc[8] = {};
#pragma unroll
    for (int kt = 0; kt < 4; ++kt) {
      bf16x8 bv[8];
#pragma unroll
      for (int n = 0; n < 8; ++n) {
        int rk = n * 16 + l15;
        bv[n] = *(const bf16x8*)(sK + rk * 256 + (((kt * 4 + lq) ^ (rk & 15)) * 16));
      }
#pragma unroll
      for (int n = 0; n < 8; ++n)
        sacc[n] = __builtin_amdgcn_mfma_f32_16x16x32_bf16(qf[kt], bv[n], sacc[n], 0, 0, 0);
    }

    if (jj == jmax) {
#pragma unroll
      for (int n = 0; n < 8; ++n)
#pragma unroll
        for (int j = 0; j < 4; ++j) {
          int qrow = qlo + wid16 + lq * 4 + j;
          int kcol = jj * KVB + n * 16 + l15;
          if (kcol > qrow) sacc[n][j] = -3.0e38f;
        }
    }

#pragma unroll
    for (int j = 0; j < 4; ++j) {
      float mx = sacc[0][j];
#pragma unroll
      for (int n = 1; n < 8; ++n) mx = fmaxf(mx, sacc[n][j]);
#pragma unroll
      for (int off = 1; off < 16; off <<= 1) mx = fmaxf(mx, __shfl_xor(mx, off, 64));
      float mnew = fmaxf(m_run[j], mx);
      float corr = exp2f((m_run[j] - mnew) * sl2e);
      m_run[j] = mnew;
      float ps = 0.f;
#pragma unroll
      for (int n = 0; n < 8; ++n) {
        float p = exp2f((sacc[n][j] - mnew) * sl2e);
        sacc[n][j] = p;
        ps += p;
      }
#pragma unroll
      for (int off = 1; off < 16; off <<= 1) ps += __shfl_xor(ps, off, 64);
      l_run[j] = l_run[j] * corr + ps;
#pragma unroll
      for (int n = 0; n < 8; ++n) oacc[n][j] *= corr;
    }

#pragma unroll
    for (int n = 0; n < 8; ++n)
#pragma unroll
      for (int j = 0; j < 4; ++j) {
        int row = wid16 + lq * 4 + j;
        int col = n * 16 + l15;
        int c16 = (col >> 3) ^ (row & 15);
        *(bf16*)(sP + row * 256 + c16 * 16 + (col & 7) * 2) = (bf16)sacc[n][j];
      }
    __syncthreads();

#pragma unroll
    for (int kt = 0; kt < 4; ++kt) {
      const int prow = wid16 + l15;
      bf16x8 av = *(const bf16x8*)(sP + prow * 256 + (((kt * 4 + lq) ^ (prow & 15)) * 16));
      bf16x8 bv[8];
#pragma unroll
      for (int n = 0; n < 8; ++n) {
        int rd = n * 16 + l15;
        bv[n] = *(const bf16x8*)(sV + rd * 256 + (((kt * 4 + lq) ^ (rd & 15)) * 16));
      }
#pragma unroll
      for (int n = 0; n < 8; ++n)
        oacc[n] = __builtin_amdgcn_mfma_f32_16x16x32_bf16(av, bv[n], oacc[n], 0, 0, 0);
    }
    __syncthreads();
  }

#pragma unroll
  for (int j = 0; j < 4; ++j) {
    int row = qlo + wid16 + lq * 4 + j;
    float inv = 1.f / l_run[j];
#pragma unroll
    for (int n = 0; n < 8; ++n) {
      int col = h * cHD + n * 16 + l15;
      outb[((int64_t)b * cK + row) * cD + col] = (bf16)(oacc[n][j] * inv);
    }
  }
}

// ---------------- elementwise / staging kernels ----------------
__global__ void copy_skip(const float4* __restrict__ s, float4* __restrict__ d,
                          const unsigned char* __restrict__ flags, int64_t n) {
  int64_t i = (int64_t)blockIdx.x * blockDim.x + threadIdx.x;
  const int64_t st = (int64_t)gridDim.x * blockDim.x;
  for (; i < n; i += st) {
    int row = (int)(i >> 9);
    if (!flags[row]) d[i] = s[i];
  }
}

__global__ void build_flags(const int* __restrict__ topk, unsigned char* __restrict__ flags) {
  int r = blockIdx.x * 256 + threadIdx.x;
  if (r < cM) flags[(r >> 10) * cT + topk[r]] = 1;
}

// fp32 (R,C) -> bf16 (C,R) with column offset into a concat buffer
__global__ void wconv(const float* __restrict__ src, bf16* __restrict__ dst,
                      int R, int C, int coff, int ldd) {
  __shared__ float t[32][33];
  const int c0 = blockIdx.x * 32, r0 = blockIdx.y * 32;
  for (int rr = threadIdx.y; rr < 32; rr += 8)
    t[rr][threadIdx.x] = src[(int64_t)(r0 + rr) * C + c0 + threadIdx.x];
  __syncthreads();
  for (int rr = threadIdx.y; rr < 32; rr += 8)
    dst[(int64_t)(c0 + rr + coff) * ldd + r0 + threadIdx.x] = (bf16)t[threadIdx.x][rr];
}

// gate/up fp32 (cD, cFF) -> B' bf16 (2*cFF, cD), 16-rows-G / 16-rows-U interleaved:
// gate col c -> B'-row ((c&~15)<<1)|(c&15); up col c -> +16.
__global__ void wconv_gu(const float* __restrict__ srcG, const float* __restrict__ srcU,
                         bf16* __restrict__ dst) {
  __shared__ float t[32][33];
  const float* src = blockIdx.z ? srcU : srcG;
  const int c0 = blockIdx.x * 32, r0 = blockIdx.y * 32;
  for (int rr = threadIdx.y; rr < 32; rr += 8)
    t[rr][threadIdx.x] = src[(int64_t)(r0 + rr) * cFF + c0 + threadIdx.x];
  __syncthreads();
  for (int rr = threadIdx.y; rr < 32; rr += 8) {
    int c = c0 + rr;
    int dr = ((c & ~15) << 1) | (blockIdx.z ? 16 : 0) | (c & 15);
    dst[(int64_t)dr * cD + r0 + threadIdx.x] = (bf16)t[threadIdx.x][rr];
  }
}

__global__ void biascat(const float* __restrict__ bq, const float* __restrict__ bk,
                        const float* __restrict__ bv, float* __restrict__ o) {
  int i = blockIdx.x * 256 + threadIdx.x;
  if (i < QKVW) o[i] = (i < 2048) ? bq[i] : (i < 2560 ? bk[i - 2048] : bv[i - 2560]);
}

__global__ void rmsnorm_rows(const float* __restrict__ base, const int* __restrict__ topk,
                             const float* __restrict__ w, bf16* __restrict__ out) {
  const int r = blockIdx.x;
  const float* src;
  if (topk) {
    int t = topk[r];
    src = base + ((int64_t)(r >> 10) * cT + t) * cD;
  } else {
    src = base + (int64_t)r * cD;
  }
  const int tid = threadIdx.x;
  const float4* s4 = (const float4*)src;
  float4 a = s4[tid * 2], b = s4[tid * 2 + 1];
  float ss = a.x * a.x + a.y * a.y + a.z * a.z + a.w * a.w +
             b.x * b.x + b.y * b.y + b.z * b.z + b.w * b.w;
  float tot = blk_reduce<0>(ss);
  float sc = rsqrtf(tot * (1.f / cD) + 1e-6f);
  bf16* o = out + (int64_t)r * cD;
  const int d0 = tid * 8;
  o[d0 + 0] = (bf16)(a.x * sc * w[d0 + 0]);
  o[d0 + 1] = (bf16)(a.y * sc * w[d0 + 1]);
  o[d0 + 2] = (bf16)(a.z * sc * w[d0 + 2]);
  o[d0 + 3] = (bf16)(a.w * sc * w[d0 + 3]);
  o[d0 + 4] = (bf16)(b.x * sc * w[d0 + 4]);
  o[d0 + 5] = (bf16)(b.y * sc * w[d0 + 5]);
  o[d0 + 6] = (bf16)(b.z * sc * w[d0 + 6]);
  o[d0 + 7] = (bf16)(b.w * sc * w[d0 + 7]);
}

__global__ void rope_kernel(bf16* __restrict__ qkv, const float* __restrict__ cosb,
                            const float* __restrict__ sinb, const int* __restrict__ topk) {
  const int r = blockIdx.x;
  const int b = r >> 10;
  const int t = topk[r];
  const float* cr = cosb + ((int64_t)b * cT + t) * cHD;
  const float* sr = sinb + ((int64_t)b * cT + t) * cHD;
  bf16* rowq = qkv + (int64_t)r * QKVW;
  for (int p = threadIdx.x; p < (cH + cKVH) * 64; p += 256) {
    int hh = p >> 6, d = p & 63;
    bf16* base = (hh < cH) ? (rowq + hh * cHD) : (rowq + cH * cHD + (hh - cH) * cHD);
    float x1 = (float)base[d], x2 = (float)base[d + 64];
    float c1 = cr[d], s1 = sr[d], c2 = cr[d + 64], s2 = sr[d + 64];
    base[d] = (bf16)(x1 * c1 - x2 * s1);
    base[d + 64] = (bf16)(x2 * c2 + x1 * s2);
  }
}

__global__ void vtrans(const bf16* __restrict__ qkv, bf16* __restrict__ Vt) {
  __shared__ bf16 t[32][33];
  const int bz = blockIdx.z, b = bz >> 2, kv = bz & 3;
  const int k0 = blockIdx.x * 32, d0 = blockIdx.y * 32;
  for (int rr = threadIdx.y; rr < 32; rr += 8)
    t[rr][threadIdx.x] =
        qkv[(int64_t)(b * cK + k0 + rr) * QKVW + cH * cHD + cKVH * cHD + kv * cHD + d0 + threadIdx.x];
  __syncthreads();
  for (int rr = threadIdx.y; rr < 32; rr += 8)
    Vt[((int64_t)(b * cKVH + kv) * cHD + d0 + rr) * cK + k0 + threadIdx.x] = t[threadIdx.x][rr];
}

}  // namespace

extern "C" void kernel_launch(void* const* d_in, const int* in_sizes, int n_in,
                              void* d_out, int out_size, void* d_ws, size_t ws_size,
                              hipStream_t stream) {
  const float* hidden = (const float*)d_in[0];
  const int* topk = (const int*)d_in[1];
  const float* gating = (const float*)d_in[2];
  const float* cosb = (const float*)d_in[3];
  const float* sinb = (const float*)d_in[4];
  const float* Wq = (const float*)d_in[5];
  const float* bq = (const float*)d_in[6];
  const float* Wk = (const float*)d_in[7];
  const float* bk = (const float*)d_in[8];
  const float* Wv = (const float*)d_in[9];
  const float* bv = (const float*)d_in[10];
  const float* Wo = (const float*)d_in[11];
  const float* wg = (const float*)d_in[12];
  const float* wu = (const float*)d_in[13];
  const float* wd = (const float*)d_in[14];
  const float* ln1 = (const float*)d_in[15];
  const float* ln2 = (const float*)d_in[16];
  float* out = (float*)d_out;
  (void)in_sizes; (void)n_in; (void)out_size; (void)ws_size;

  char* ws = (char*)d_ws;
  size_t off = 0;
  auto alloc = [&](size_t bytes) {
    char* p = ws + off;
    off += (bytes + 255) & ~(size_t)255;
    return p;
  };
  bf16* wt_qkv = (bf16*)alloc((size_t)QKVW * cD * 2);
  bf16* wt_o = (bf16*)alloc((size_t)cD * cD * 2);
  bf16* wt_gu = (bf16*)alloc((size_t)2 * cFF * cD * 2);
  bf16* wt_d = (bf16*)alloc((size_t)cD * cFF * 2);
  float* bias_cat = (float*)alloc((size_t)QKVW * 4);
  bf16* hbuf = (bf16*)alloc((size_t)cM * cD * 2);
  bf16* qkv = (bf16*)alloc((size_t)cM * QKVW * 2);
  bf16* vt = (bf16*)alloc((size_t)cB * cKVH * cHD * cK * 2);
  bf16* attnout = (bf16*)alloc((size_t)cM * cD * 2);
  float* xbuf = (float*)alloc((size_t)cM * cD * 4);
  bf16* actbuf = (bf16*)alloc((size_t)cM * cFF * 2);
  unsigned char* flags = (unsigned char*)alloc((size_t)cB * cT);

  // flags = selected-row mask; copy only unselected rows (EpiDown writes selected)
  (void)hipMemsetAsync(flags, 0, (size_t)cB * cT, stream);
  build_flags<<<cM / 256, 256, 0, stream>>>(topk, flags);
  copy_skip<<<2048, 256, 0, stream>>>((const float4*)hidden, (float4*)out, flags,
                                      (int64_t)cB * cT * cD / 4);

  const dim3 tb(32, 8);
  wconv<<<dim3(cD / 32, cD / 32), tb, 0, stream>>>(Wq, wt_qkv, cD, cD, 0, cD);
  wconv<<<dim3(512 / 32, cD / 32), tb, 0, stream>>>(Wk, wt_qkv, cD, 512, 2048, cD);
  wconv<<<dim3(512 / 32, cD / 32), tb, 0, stream>>>(Wv, wt_qkv, cD, 512, 2560, cD);
  wconv<<<dim3(cD / 32, cD / 32), tb, 0, stream>>>(Wo, wt_o, cD, cD, 0, cD);
  wconv_gu<<<dim3(cFF / 32, cD / 32, 2), tb, 0, stream>>>(wg, wu, wt_gu);
  wconv<<<dim3(cD / 32, cFF / 32), tb, 0, stream>>>(wd, wt_d, cFF, cD, 0, cFF);
  biascat<<<(QKVW + 255) / 256, 256, 0, stream>>>(bq, bk, bv, bias_cat);

  // gather + rmsnorm1
  rmsnorm_rows<<<cM, 256, 0, stream>>>(hidden, topk, ln1, hbuf);
  // qkv projection (+bias)   [pair-mode pipeline]
  gemm256<256, 2, 4, 5, 2, EpiQKV><<<16 * (QKVW / 256), 512, 0, stream>>>(
      hbuf, cD, wt_qkv, cD, cD, 16, EpiQKV{qkv, bias_cat});
  rope_kernel<<<cM, 256, 0, stream>>>(qkv, cosb, sinb, topk);
  vtrans<<<dim3(cK / 32, cHD / 32, cB * cKVH), tb, 0, stream>>>(qkv, vt);

  // fused flash attention (1D grid, XCD-chunked remap for KV L2 locality)
  flash_attn<<<1024, 256, 0, stream>>>(qkv, vt, attnout);

  // o-proj + gathered residual -> x (fp32)   [pair-mode pipeline]
  gemm256<128, 4, 2, 5, 2, EpiOProj><<<16 * (cD / 128), 512, 0, stream>>>(
      attnout, cD, wt_o, cD, cD, 16, EpiOProj{xbuf, hidden, topk});
  // rmsnorm2
  rmsnorm_rows<<<cM, 256, 0, stream>>>(xbuf, nullptr, ln2, hbuf);
  // fused gate+up -> act = silu(gate)*up   [8-phase m201-style schedule, session best]
  gemm_gateup8<<<16 * (2 * cFF / 256), 512, 0, stream>>>(hbuf, wt_gu, actbuf);
  // down + residual + gating + scatter into d_out   [pair-mode pipeline]
  gemm256<128, 4, 2, 5, 2, EpiDown><<<16 * (cD / 128), 512, 0, stream>>>(
      actbuf, cFF, wt_d, cFF, cFF, 16, EpiDown{out, xbuf, hidden, topk, gating});
}

// Round 18
// 821.450 us; speedup vs baseline: 1.0811x; 1.0174x over previous
//
#include <hip/hip_runtime.h>
#include <stdint.h>

typedef __bf16 bf16;
typedef __attribute__((ext_vector_type(8))) __bf16 bf16x8;
typedef __attribute__((ext_vector_type(4))) float f32x4;

namespace {

constexpr int cB = 4, cT = 4096, cD = 2048, cK = 1024, cH = 16, cKVH = 4, cHD = 128, cFF = 8192;
constexpr int cM = cB * cK;                 // 4096 gathered rows
constexpr int QKVW = cH * cHD + 2 * cKVH * cHD; // 3072

__device__ __forceinline__ void load_lds16(const void* g, void* l) {
  __builtin_amdgcn_global_load_lds((const __attribute__((address_space(1))) void*)g,
                                   (__attribute__((address_space(3))) void*)l, 16, 0, 0);
}

template <int N>
__device__ __forceinline__ void waitcnt_vm() {
  if constexpr (N == 0) asm volatile("s_waitcnt vmcnt(0)" ::: "memory");
  else if constexpr (N == 2) asm volatile("s_waitcnt vmcnt(2)" ::: "memory");
  else if constexpr (N == 3) asm volatile("s_waitcnt vmcnt(3)" ::: "memory");
  else if constexpr (N == 4) asm volatile("s_waitcnt vmcnt(4)" ::: "memory");
  else if constexpr (N == 6) asm volatile("s_waitcnt vmcnt(6)" ::: "memory");
  else if constexpr (N == 8) asm volatile("s_waitcnt vmcnt(8)" ::: "memory");
  else static_assert(N == 0, "unsupported vmcnt literal");
}

// ---------------- block reduce (256 threads = 4 waves) ----------------
template <int OP>  // 0 = sum, 1 = max
__device__ __forceinline__ float blk_reduce(float v) {
  __shared__ float sm[5];
  const int tid = threadIdx.x, lane = tid & 63, wid = tid >> 6;
#pragma unroll
  for (int o = 32; o; o >>= 1) {
    float o2 = __shfl_down(v, o, 64);
    v = OP ? fmaxf(v, o2) : v + o2;
  }
  if (lane == 0) sm[wid] = v;
  __syncthreads();
  if (tid == 0) {
    float r = sm[0];
#pragma unroll
    for (int i = 1; i < 4; ++i) r = OP ? fmaxf(r, sm[i]) : r + sm[i];
    sm[4] = r;
  }
  __syncthreads();
  float r = sm[4];
  __syncthreads();
  return r;
}

// ================= deep-pipelined 256-row MFMA GEMM: C = A * B^T =================
// (pair-mode, proven) — used for QKV / OProj.
template <int BN, int WM, int WN, int RING, int UNROLL, class Epi>
__global__ __launch_bounds__(512, 2)
void gemm256(const bf16* __restrict__ A, int lda,
             const bf16* __restrict__ Bm, int ldb,
             int Kd, int GM, Epi epi) {
  constexpr int BM = 256;
  constexpr int FM = BM / WM / 16;
  constexpr int FN = BN / WN / 16;
  constexpr int ACALLS = 2;
  constexpr int BCALLS = BN / 128;
  constexpr int L = ACALLS + BCALLS;
  constexpr int D = RING - 1;
  constexpr int SLOTA = BM * 64;
  constexpr int SLOTB = BN * 64;
  constexpr int SLOT = SLOTA + SLOTB;
  __shared__ __align__(16) char lds[RING * SLOT];

  const int tid = threadIdx.x;
  const int lane = tid & 63;
  const int wid = tid >> 6;
  const int l15 = lane & 15, lq = lane >> 4;
  const int wr = wid / WN, wc = wid % WN;

  const int nwg = gridDim.x;
  const int xcd = blockIdx.x & 7, loc = blockIdx.x >> 3;
  const int wg = xcd * (nwg >> 3) + loc;
  const int GN = nwg / GM;
  const int per = 8 * GN;
  const int g = wg / per, r = wg % per;
  const int bm = g * 8 + (r & 7);
  const int bn = r >> 3;

  const bf16* Abase = A + (int64_t)bm * BM * lda;
  const bf16* Bbase = Bm + (int64_t)bn * BN * ldb;

  const bf16* srcA[ACALLS];
  int dstA[ACALLS];
#pragma unroll
  for (int c2 = 0; c2 < ACALLS; ++c2) {
    const int chunk = c2 * 512 + tid;
    const int row = chunk >> 2, pc = chunk & 3;
    const int lc = pc ^ ((row >> 1) & 3);
    srcA[c2] = Abase + (int64_t)row * lda + lc * 8;
    dstA[c2] = chunk * 16;
  }
  const bf16* srcB[BCALLS];
  int dstB[BCALLS];
#pragma unroll
  for (int c2 = 0; c2 < BCALLS; ++c2) {
    const int chunk = c2 * 512 + tid;
    const int row = chunk >> 2, pc = chunk & 3;
    const int lc = pc ^ ((row >> 1) & 3);
    srcB[c2] = Bbase + (int64_t)row * ldb + lc * 8;
    dstB[c2] = chunk * 16;
  }

  int offA[FM], offB[FN];
#pragma unroll
  for (int m = 0; m < FM; ++m) {
    const int row = wr * (BM / WM) + m * 16 + l15;
    offA[m] = row * 64 + (lq ^ ((row >> 1) & 3)) * 16;
  }
#pragma unroll
  for (int n = 0; n < FN; ++n) {
    const int row = wc * (BN / WN) + n * 16 + l15;
    offB[n] = SLOTA + row * 64 + (lq ^ ((row >> 1) & 3)) * 16;
  }

  const int KT = Kd >> 5;
  auto stage = [&](int t) {
    char* sb = lds + (size_t)(t % RING) * SLOT;
#pragma unroll
    for (int c2 = 0; c2 < ACALLS; ++c2)
      load_lds16(srcA[c2] + t * 32, sb + dstA[c2]);
#pragma unroll
    for (int c2 = 0; c2 < BCALLS; ++c2)
      load_lds16(srcB[c2] + t * 32, sb + SLOTA + dstB[c2]);
  };
  auto compute = [&](int t, f32x4 (&acc)[FM][FN]) {
    const char* sb = lds + (size_t)(t % RING) * SLOT;
    bf16x8 av[FM], bv[FN];
#pragma unroll
    for (int m = 0; m < FM; ++m) av[m] = *(const bf16x8*)(sb + offA[m]);
#pragma unroll
    for (int n = 0; n < FN; ++n) bv[n] = *(const bf16x8*)(sb + offB[n]);
    __builtin_amdgcn_s_setprio(1);
#pragma unroll
    for (int m = 0; m < FM; ++m)
#pragma unroll
      for (int n = 0; n < FN; ++n)
        acc[m][n] = __builtin_amdgcn_mfma_f32_16x16x32_bf16(av[m], bv[n], acc[m][n], 0, 0, 0);
    __builtin_amdgcn_s_setprio(0);
  };

  f32x4 acc[FM][FN] = {};

  if constexpr (UNROLL == 1) {
#pragma unroll
    for (int i = 0; i < D; ++i) stage(i);
    waitcnt_vm<(D - 1) * L>();
    __builtin_amdgcn_s_barrier();
    __builtin_amdgcn_sched_barrier(0);
    for (int t = 0; t < KT - D; ++t) {
      stage(t + D);
      compute(t, acc);
      waitcnt_vm<(D - 1) * L>();
      __builtin_amdgcn_s_barrier();
      __builtin_amdgcn_sched_barrier(0);
    }
    waitcnt_vm<0>();
    __builtin_amdgcn_s_barrier();
    for (int t = KT - D; t < KT; ++t) compute(t, acc);
  } else {
    static_assert(RING == 5 && UNROLL == 2, "pair mode is RING=5");
#pragma unroll
    for (int i = 0; i < 3; ++i) stage(i);
    waitcnt_vm<L>();
    __builtin_amdgcn_s_barrier();
    __builtin_amdgcn_sched_barrier(0);
    int t = 0;
    for (; t <= KT - 6; t += 2) {
      stage(t + 3);
      stage(t + 4);
      compute(t, acc);
      compute(t + 1, acc);
      waitcnt_vm<L>();
      __builtin_amdgcn_s_barrier();
      __builtin_amdgcn_sched_barrier(0);
    }
    stage(KT - 1);
    waitcnt_vm<0>();
    __builtin_amdgcn_s_barrier();
    compute(KT - 4, acc);
    compute(KT - 3, acc);
    compute(KT - 2, acc);
    compute(KT - 1, acc);
  }

#pragma unroll
  for (int m = 0; m < FM; ++m) {
    const int r0 = bm * BM + wr * (BM / WM) + m * 16 + lq * 4;
#pragma unroll
    for (int n = 0; n < FN; ++n) {
      const int c1 = bn * BN + wc * (BN / WN) + n * 16 + l15;
#pragma unroll
      for (int j = 0; j < 4; ++j) epi(r0 + j, c1, acc[m][n][j]);
    }
  }
}

// ========== 8-phase fused gate+up GEMM (m201 schedule port — session best) ==========
__global__ __launch_bounds__(512, 2)
void gemm_gateup8(const bf16* __restrict__ A, const bf16* __restrict__ Bgu,
                  bf16* __restrict__ act) {
  constexpr int QSZ = 64 * 128;  // quarter: 64 rows x 128 B = 8 KB
  __shared__ __align__(16) char lds[2 * 8 * QSZ];  // 128 KB

  const int tid = threadIdx.x, lane = tid & 63;
  const int wid = tid >> 6;
  const int l15 = lane & 15, lq = lane >> 4;
  const int wr = wid >> 2, wc = wid & 3;  // 2 x 4 wave grid

  const int nwg = gridDim.x;
  const int xcd = blockIdx.x & 7, loc = blockIdx.x >> 3;
  const int wg = xcd * (nwg >> 3) + loc;
  const int GM = 16, GN = nwg / GM;
  const int per = 8 * GN;
  const int g = wg / per, r = wg % per;
  const int bm = g * 8 + (r & 7);
  const int bn = r >> 3;

  const bf16* Abase = A + (int64_t)bm * 256 * cD;
  const bf16* Bbase = Bgu + (int64_t)bn * 256 * cD;

  const int srow = tid >> 3, spc = tid & 7;
  const int slc = spc ^ (srow & 7);  // pre-swizzled global k-chunk
  const int sdst = tid * 16;
  const bf16* qsrc[8];
#pragma unroll
  for (int q = 0; q < 4; ++q) qsrc[q] = Abase + (int64_t)(q * 64 + srow) * cD + slc * 8;
#pragma unroll
  for (int q = 0; q < 4; ++q) qsrc[4 + q] = Bbase + (int64_t)(q * 64 + srow) * cD + slc * 8;

  auto stageQ = [&](int buf, int q, int kt) {
    load_lds16(qsrc[q] + kt * 64, lds + (size_t)(buf * 8 + q) * QSZ + sdst);
  };

  f32x4 acc[8][4] = {};
  bf16x8 af[4][2], bfr[2][2];

  auto ldA = [&](int buf, int qr) {
    const char* qb = lds + (size_t)(buf * 8 + wr * 2 + qr) * QSZ;
#pragma unroll
    for (int mq = 0; mq < 4; ++mq) {
      const int rr = mq * 16 + l15;
#pragma unroll
      for (int ks = 0; ks < 2; ++ks)
        af[mq][ks] = *(const bf16x8*)(qb + rr * 128 + (((ks * 4 + lq) ^ (rr & 7)) * 16));
    }
  };
  auto ldB = [&](int buf, int qc) {
    const char* qb = lds + (size_t)(buf * 8 + 4 + wc) * QSZ;
#pragma unroll
    for (int nq = 0; nq < 2; ++nq) {
      const int rr = qc * 32 + nq * 16 + l15;
#pragma unroll
      for (int ks = 0; ks < 2; ++ks)
        bfr[nq][ks] = *(const bf16x8*)(qb + rr * 128 + (((ks * 4 + lq) ^ (rr & 7)) * 16));
    }
  };
  auto mfma16 = [&](int qr, int qc) {
    __builtin_amdgcn_s_setprio(1);
#pragma unroll
    for (int ks = 0; ks < 2; ++ks)
#pragma unroll
      for (int mq = 0; mq < 4; ++mq)
#pragma unroll
        for (int nq = 0; nq < 2; ++nq)
          acc[qr * 4 + mq][qc * 2 + nq] = __builtin_amdgcn_mfma_f32_16x16x32_bf16(
              af[mq][ks], bfr[nq][ks], acc[qr * 4 + mq][qc * 2 + nq], 0, 0, 0);
    __builtin_amdgcn_s_setprio(0);
  };

  const int KT = cD >> 6;  // 32 K-tiles of 64

  stageQ(0, 4, 0); stageQ(0, 5, 0);
  stageQ(0, 6, 0); stageQ(0, 7, 0);
  stageQ(0, 0, 0); stageQ(0, 2, 0);
  stageQ(0, 1, 0); stageQ(0, 3, 0);
  waitcnt_vm<2>();
  __builtin_amdgcn_s_barrier();

  for (int t = 0; t < KT; ++t) {
    const int buf = t & 1, nb = buf ^ 1;
    const bool more = (t + 1 < KT);
    ldA(buf, 0);
    ldB(buf, 0);
    if (more) { stageQ(nb, 4, t + 1); stageQ(nb, 5, t + 1); }
    __builtin_amdgcn_s_barrier();
    mfma16(0, 0);
    __builtin_amdgcn_s_barrier();
    ldB(buf, 1);
    if (more) { stageQ(nb, 6, t + 1); stageQ(nb, 7, t + 1); }
    __builtin_amdgcn_s_barrier();
    mfma16(0, 1);
    if (more) waitcnt_vm<4>();
    else      waitcnt_vm<0>();
    __builtin_amdgcn_s_barrier();
    ldA(buf, 1);
    if (more) { stageQ(nb, 0, t + 1); stageQ(nb, 2, t + 1); }
    __builtin_amdgcn_s_barrier();
    mfma16(1, 1);
    __builtin_amdgcn_s_barrier();
    ldB(buf, 0);
    if (more) { stageQ(nb, 1, t + 1); stageQ(nb, 3, t + 1); }
    __builtin_amdgcn_s_barrier();
    mfma16(1, 0);
    if (more) waitcnt_vm<2>();
    __builtin_amdgcn_s_barrier();
  }

#pragma unroll
  for (int m = 0; m < 8; ++m) {
    const int row = bm * 256 + wr * 128 + (m >> 2) * 64 + (m & 3) * 16 + lq * 4;
#pragma unroll
    for (int p = 0; p < 2; ++p) {
      const int col = bn * 128 + wc * 32 + p * 16 + l15;
#pragma unroll
      for (int j = 0; j < 4; ++j) {
        float gv = acc[m][2 * p][j];
        float s = gv / (1.f + __expf(-gv));
        act[(int64_t)(row + j) * cFF + col] = (bf16)(s * acc[m][2 * p + 1][j]);
      }
    }
  }
}

// ========== down8: deep-K 2-phase double-buffered Down GEMM (round 18) ==========
// C = actbuf(4096x8192) * wt_d(2048x8192)^T + EpiDown scatter. BM=256, BN=128, BK=64,
// KT=128 — deep K is where the phase pipeline amortizes (m201 regime). Grid 256 =
// 16bm x 16bn = one full GPU wave, grouped-XCD mapping. 8 waves 2x4: wave = 128 A-rows
// x 32 B-rows. acc[8][2]=64 regs. LDS 2 bufs x 6 quarters (A:4,B:2) x 8KB = 96 KB.
// B frags loaded once per tile (held in regs across both phases).
// Per tile: p0 {ldB+ldA(h0) | stage Bq0,Bq1,Aq0(t+1) | bar | 16 MFMA | vmcnt(3) | bar}
//           p1 {ldA(h1)     | stage Aq2,Aq1,Aq3(t+1) | bar | 16 MFMA | vmcnt(2) | bar}
// vmcnt ledger (1 load/thread/quarter; issue order B0,B1,A0 | A2,A1,A3):
//   end-p0: outstanding [Aq1,Aq3(t), Bq0,Bq1,Aq0(t+1)]=5 -> vmcnt(3) retires Aq13(t)
//           (needed by p1); TAIL t=KT-1: vmcnt(0).
//   end-p1: outstanding 6 of (t+1) -> vmcnt(2) retires Bq01,Aq0,Aq2(t+1) (needed by
//           (t+1)-p0). Never 0 in steady loop. Prologue: 6 stages + vmcnt(2) + bar.
__global__ __launch_bounds__(512, 2)
void gemm_down8(const bf16* __restrict__ A, const bf16* __restrict__ Bm,
                float* __restrict__ out, const float* __restrict__ x,
                const float* __restrict__ hidden, const int* __restrict__ topk,
                const float* __restrict__ gating) {
  constexpr int QSZ = 64 * 128;  // 8 KB
  __shared__ __align__(16) char lds[2 * 6 * QSZ];  // 96 KB

  const int tid = threadIdx.x, lane = tid & 63;
  const int wid = tid >> 6;
  const int l15 = lane & 15, lq = lane >> 4;
  const int wr = wid >> 2, wc = wid & 3;  // 2 x 4 wave grid

  // grouped-XCD mapping (nwg = 256, GM = 16, GN = 16)
  const int nwg = gridDim.x;
  const int xcd = blockIdx.x & 7, loc = blockIdx.x >> 3;
  const int wg = xcd * (nwg >> 3) + loc;
  const int GM = 16, GN = nwg / GM;
  const int per = 8 * GN;
  const int g = wg / per, r = wg % per;
  const int bm = g * 8 + (r & 7);
  const int bn = r >> 3;

  const bf16* Abase = A + (int64_t)bm * 256 * cFF;
  const bf16* Bbase = Bm + (int64_t)bn * 128 * cFF;

  const int srow = tid >> 3, spc = tid & 7;
  const int slc = spc ^ (srow & 7);
  const int sdst = tid * 16;
  const bf16* qsrc[6];
#pragma unroll
  for (int q = 0; q < 4; ++q) qsrc[q] = Abase + (int64_t)(q * 64 + srow) * cFF + slc * 8;
#pragma unroll
  for (int q = 0; q < 2; ++q) qsrc[4 + q] = Bbase + (int64_t)(q * 64 + srow) * cFF + slc * 8;

  auto stageQ = [&](int buf, int q, int kt) {
    load_lds16(qsrc[q] + kt * 64, lds + (size_t)(buf * 6 + q) * QSZ + sdst);
  };

  f32x4 acc[8][2] = {};
  bf16x8 af[4][2], bfr[2][2];

  auto ldA = [&](int buf, int half) {
    const char* qb = lds + (size_t)(buf * 6 + wr * 2 + half) * QSZ;
#pragma unroll
    for (int mq = 0; mq < 4; ++mq) {
      const int rr = mq * 16 + l15;
#pragma unroll
      for (int ks = 0; ks < 2; ++ks)
        af[mq][ks] = *(const bf16x8*)(qb + rr * 128 + (((ks * 4 + lq) ^ (rr & 7)) * 16));
    }
  };
  auto ldB = [&](int buf) {
    const char* qb = lds + (size_t)(buf * 6 + 4 + (wc >> 1)) * QSZ;
#pragma unroll
    for (int nq = 0; nq < 2; ++nq) {
      const int rr = (wc & 1) * 32 + nq * 16 + l15;
#pragma unroll
      for (int ks = 0; ks < 2; ++ks)
        bfr[nq][ks] = *(const bf16x8*)(qb + rr * 128 + (((ks * 4 + lq) ^ (rr & 7)) * 16));
    }
  };
  auto mfma16 = [&](int half) {
    __builtin_amdgcn_s_setprio(1);
#pragma unroll
    for (int ks = 0; ks < 2; ++ks)
#pragma unroll
      for (int mq = 0; mq < 4; ++mq)
#pragma unroll
        for (int nq = 0; nq < 2; ++nq)
          acc[half * 4 + mq][nq] = __builtin_amdgcn_mfma_f32_16x16x32_bf16(
              af[mq][ks], bfr[nq][ks], acc[half * 4 + mq][nq], 0, 0, 0);
    __builtin_amdgcn_s_setprio(0);
  };

  const int KT = cFF >> 6;  // 128 K-tiles of 64

  // prologue: tile 0 quarters in retirement order
  stageQ(0, 4, 0); stageQ(0, 5, 0); stageQ(0, 0, 0);  // Bq0,Bq1,Aq0
  stageQ(0, 2, 0); stageQ(0, 1, 0); stageQ(0, 3, 0);  // Aq2,Aq1,Aq3
  waitcnt_vm<2>();
  __builtin_amdgcn_s_barrier();

  for (int t = 0; t < KT; ++t) {
    const int buf = t & 1, nb = buf ^ 1;
    const bool more = (t + 1 < KT);
    // phase 0: A half 0 x B
    ldB(buf);
    ldA(buf, 0);
    if (more) { stageQ(nb, 4, t + 1); stageQ(nb, 5, t + 1); stageQ(nb, 0, t + 1); }
    __builtin_amdgcn_s_barrier();
    mfma16(0);
    if (more) waitcnt_vm<3>();
    else      waitcnt_vm<0>();  // tail: retire Aq1,Aq3 of the last tile
    __builtin_amdgcn_s_barrier();
    // phase 1: A half 1 x B (bfr held in regs)
    ldA(buf, 1);
    if (more) { stageQ(nb, 2, t + 1); stageQ(nb, 1, t + 1); stageQ(nb, 3, t + 1); }
    __builtin_amdgcn_s_barrier();
    mfma16(1);
    if (more) waitcnt_vm<2>();
    __builtin_amdgcn_s_barrier();
  }

  // epilogue: x2 = x + acc; upd = sel + (x2-sel)*gate; scatter to d_out
#pragma unroll
  for (int m = 0; m < 8; ++m) {
    const int row = bm * 256 + wr * 128 + (m >> 2) * 64 + (m & 3) * 16 + lq * 4;
#pragma unroll
    for (int nq = 0; nq < 2; ++nq) {
      const int col = bn * 128 + wc * 32 + nq * 16 + l15;
#pragma unroll
      for (int j = 0; j < 4; ++j) {
        const int rr = row + j;
        const int b = rr >> 10;
        const int tk = topk[rr];
        float x2 = acc[m][nq][j] + x[(int64_t)rr * cD + col];
        int64_t ho = ((int64_t)b * cT + tk) * cD + col;
        float sel = hidden[ho];
        out[ho] = sel + (x2 - sel) * gating[rr];
      }
    }
  }
}

// ---------------- epilogues ----------------
struct EpiQKV {
  bf16* out; const float* bias;
  __device__ void operator()(int r, int c, float v) const {
    out[(int64_t)r * QKVW + c] = (bf16)(v + bias[c]);
  }
};
struct EpiOProj {
  float* x; const float* hidden; const int* topk;
  __device__ void operator()(int r, int c, float v) const {
    int b = r >> 10;
    int t = topk[r];
    x[(int64_t)r * cD + c] = v + hidden[((int64_t)b * cT + t) * cD + c];
  }
};

// ================= fused flash attention (XCD-chunked remap) =================
__global__ __launch_bounds__(256, 2) void flash_attn(const bf16* __restrict__ qkv,
                                                     const bf16* __restrict__ vt,
                                                     bf16* __restrict__ outb) {
  constexpr int QB = 64, KVB = 128;
  __shared__ __align__(16) char lds[81920];
  char* sK = lds;            // 32 KB (also Q staging)
  char* sP = lds + 32768;    // 16 KB
  char* sV = lds + 49152;    // 32 KB

  const int xcdid = blockIdx.x & 7, locid = blockIdx.x >> 3;
  const int wg = xcdid * 128 + locid;
  const int qt = wg & 15, h = (wg >> 4) & 15, b = wg >> 8;
  const int kvh = h >> 2;
  const int qlo = qt * QB;
  const int tid = threadIdx.x, lane = tid & 63, wid = tid >> 6;
  const int l15 = lane & 15, lq = lane >> 4;
  const int wid16 = wid * 16;

  const bf16* qbase = qkv + (int64_t)(b * cK + qlo) * QKVW + h * cHD;
  const bf16* kbase = qkv + (int64_t)(b * cK) * QKVW + cH * cHD + kvh * cHD;
  const bf16* vtbase = vt + (int64_t)(b * cKVH + kvh) * cHD * cK;

#pragma unroll
  for (int c2 = 0; c2 < 4; ++c2) {
    int chunk = c2 * 256 + tid;
    int row = chunk >> 4, c16 = chunk & 15;
    load_lds16(qbase + (int64_t)row * QKVW + (c16 ^ (row & 15)) * 8, sK + chunk * 16);
  }
  __syncthreads();
  bf16x8 qf[4];
  {
    const int row = wid16 + l15;
#pragma unroll
    for (int kt = 0; kt < 4; ++kt)
      qf[kt] = *(const bf16x8*)(sK + row * 256 + (((kt * 4 + lq) ^ (row & 15)) * 16));
  }
  __syncthreads();

  f32x4 oacc[8] = {};
  float m_run[4], l_run[4];
#pragma unroll
  for (int j = 0; j < 4; ++j) { m_run[j] = -3.0e38f; l_run[j] = 0.f; }

  const int jmax = (qlo + QB - 1) >> 7;
  const float sl2e = 0.08838834764831845f * 1.44269504088896f;

  for (int jj = 0; jj <= jmax; ++jj) {
#pragma unroll
    for (int c2 = 0; c2 < 8; ++c2) {
      int chunk = c2 * 256 + tid;
      int row = chunk >> 4, c16 = chunk & 15;
      int cs = (c16 ^ (row & 15)) * 8;
      load_lds16(kbase + (int64_t)(jj * KVB + row) * QKVW + cs, sK + chunk * 16);
      load_lds16(vtbase + (int64_t)row * cK + jj * KVB + cs, sV + chunk * 16);
    }
    __syncthreads();

    f32x4 sacc[8] = {};
#pragma unroll
    for (int kt = 0; kt < 4; ++kt) {
      bf16x8 bv[8];
#pragma unroll
      for (int n = 0; n < 8; ++n) {
        int rk = n * 16 + l15;
        bv[n] = *(const bf16x8*)(sK + rk * 256 + (((kt * 4 + lq) ^ (rk & 15)) * 16));
      }
#pragma unroll
      for (int n = 0; n < 8; ++n)
        sacc[n] = __builtin_amdgcn_mfma_f32_16x16x32_bf16(qf[kt], bv[n], sacc[n], 0, 0, 0);
    }

    if (jj == jmax) {
#pragma unroll
      for (int n = 0; n < 8; ++n)
#pragma unroll
        for (int j = 0; j < 4; ++j) {
          int qrow = qlo + wid16 + lq * 4 + j;
          int kcol = jj * KVB + n * 16 + l15;
          if (kcol > qrow) sacc[n][j] = -3.0e38f;
        }
    }

#pragma unroll
    for (int j = 0; j < 4; ++j) {
      float mx = sacc[0][j];
#pragma unroll
      for (int n = 1; n < 8; ++n) mx = fmaxf(mx, sacc[n][j]);
#pragma unroll
      for (int off = 1; off < 16; off <<= 1) mx = fmaxf(mx, __shfl_xor(mx, off, 64));
      float mnew = fmaxf(m_run[j], mx);
      float corr = exp2f((m_run[j] - mnew) * sl2e);
      m_run[j] = mnew;
      float ps = 0.f;
#pragma unroll
      for (int n = 0; n < 8; ++n) {
        float p = exp2f((sacc[n][j] - mnew) * sl2e);
        sacc[n][j] = p;
        ps += p;
      }
#pragma unroll
      for (int off = 1; off < 16; off <<= 1) ps += __shfl_xor(ps, off, 64);
      l_run[j] = l_run[j] * corr + ps;
#pragma unroll
      for (int n = 0; n < 8; ++n) oacc[n][j] *= corr;
    }

#pragma unroll
    for (int n = 0; n < 8; ++n)
#pragma unroll
      for (int j = 0; j < 4; ++j) {
        int row = wid16 + lq * 4 + j;
        int col = n * 16 + l15;
        int c16 = (col >> 3) ^ (row & 15);
        *(bf16*)(sP + row * 256 + c16 * 16 + (col & 7) * 2) = (bf16)sacc[n][j];
      }
    __syncthreads();

#pragma unroll
    for (int kt = 0; kt < 4; ++kt) {
      const int prow = wid16 + l15;
      bf16x8 av = *(const bf16x8*)(sP + prow * 256 + (((kt * 4 + lq) ^ (prow & 15)) * 16));
      bf16x8 bv[8];
#pragma unroll
      for (int n = 0; n < 8; ++n) {
        int rd = n * 16 + l15;
        bv[n] = *(const bf16x8*)(sV + rd * 256 + (((kt * 4 + lq) ^ (rd & 15)) * 16));
      }
#pragma unroll
      for (int n = 0; n < 8; ++n)
        oacc[n] = __builtin_amdgcn_mfma_f32_16x16x32_bf16(av, bv[n], oacc[n], 0, 0, 0);
    }
    __syncthreads();
  }

#pragma unroll
  for (int j = 0; j < 4; ++j) {
    int row = qlo + wid16 + lq * 4 + j;
    float inv = 1.f / l_run[j];
#pragma unroll
    for (int n = 0; n < 8; ++n) {
      int col = h * cHD + n * 16 + l15;
      outb[((int64_t)b * cK + row) * cD + col] = (bf16)(oacc[n][j] * inv);
    }
  }
}

// ---------------- elementwise / staging kernels ----------------
__global__ void copy_skip(const float4* __restrict__ s, float4* __restrict__ d,
                          const unsigned char* __restrict__ flags, int64_t n) {
  int64_t i = (int64_t)blockIdx.x * blockDim.x + threadIdx.x;
  const int64_t st = (int64_t)gridDim.x * blockDim.x;
  for (; i < n; i += st) {
    int row = (int)(i >> 9);
    if (!flags[row]) d[i] = s[i];
  }
}

__global__ void build_flags(const int* __restrict__ topk, unsigned char* __restrict__ flags) {
  int r = blockIdx.x * 256 + threadIdx.x;
  if (r < cM) flags[(r >> 10) * cT + topk[r]] = 1;
}

// fp32 (R,C) -> bf16 (C,R) with column offset into a concat buffer
__global__ void wconv(const float* __restrict__ src, bf16* __restrict__ dst,
                      int R, int C, int coff, int ldd) {
  __shared__ float t[32][33];
  const int c0 = blockIdx.x * 32, r0 = blockIdx.y * 32;
  for (int rr = threadIdx.y; rr < 32; rr += 8)
    t[rr][threadIdx.x] = src[(int64_t)(r0 + rr) * C + c0 + threadIdx.x];
  __syncthreads();
  for (int rr = threadIdx.y; rr < 32; rr += 8)
    dst[(int64_t)(c0 + rr + coff) * ldd + r0 + threadIdx.x] = (bf16)t[threadIdx.x][rr];
}

// gate/up fp32 (cD, cFF) -> B' bf16 (2*cFF, cD), 16-rows-G / 16-rows-U interleaved:
// gate col c -> B'-row ((c&~15)<<1)|(c&15); up col c -> +16.
__global__ void wconv_gu(const float* __restrict__ srcG, const float* __restrict__ srcU,
                         bf16* __restrict__ dst) {
  __shared__ float t[32][33];
  const float* src = blockIdx.z ? srcU : srcG;
  const int c0 = blockIdx.x * 32, r0 = blockIdx.y * 32;
  for (int rr = threadIdx.y; rr < 32; rr += 8)
    t[rr][threadIdx.x] = src[(int64_t)(r0 + rr) * cFF + c0 + threadIdx.x];
  __syncthreads();
  for (int rr = threadIdx.y; rr < 32; rr += 8) {
    int c = c0 + rr;
    int dr = ((c & ~15) << 1) | (blockIdx.z ? 16 : 0) | (c & 15);
    dst[(int64_t)dr * cD + r0 + threadIdx.x] = (bf16)t[threadIdx.x][rr];
  }
}

__global__ void biascat(const float* __restrict__ bq, const float* __restrict__ bk,
                        const float* __restrict__ bv, float* __restrict__ o) {
  int i = blockIdx.x * 256 + threadIdx.x;
  if (i < QKVW) o[i] = (i < 2048) ? bq[i] : (i < 2560 ? bk[i - 2048] : bv[i - 2560]);
}

__global__ void rmsnorm_rows(const float* __restrict__ base, const int* __restrict__ topk,
                             const float* __restrict__ w, bf16* __restrict__ out) {
  const int r = blockIdx.x;
  const float* src;
  if (topk) {
    int t = topk[r];
    src = base + ((int64_t)(r >> 10) * cT + t) * cD;
  } else {
    src = base + (int64_t)r * cD;
  }
  const int tid = threadIdx.x;
  const float4* s4 = (const float4*)src;
  float4 a = s4[tid * 2], b = s4[tid * 2 + 1];
  float ss = a.x * a.x + a.y * a.y + a.z * a.z + a.w * a.w +
             b.x * b.x + b.y * b.y + b.z * b.z + b.w * b.w;
  float tot = blk_reduce<0>(ss);
  float sc = rsqrtf(tot * (1.f / cD) + 1e-6f);
  bf16* o = out + (int64_t)r * cD;
  const int d0 = tid * 8;
  o[d0 + 0] = (bf16)(a.x * sc * w[d0 + 0]);
  o[d0 + 1] = (bf16)(a.y * sc * w[d0 + 1]);
  o[d0 + 2] = (bf16)(a.z * sc * w[d0 + 2]);
  o[d0 + 3] = (bf16)(a.w * sc * w[d0 + 3]);
  o[d0 + 4] = (bf16)(b.x * sc * w[d0 + 4]);
  o[d0 + 5] = (bf16)(b.y * sc * w[d0 + 5]);
  o[d0 + 6] = (bf16)(b.z * sc * w[d0 + 6]);
  o[d0 + 7] = (bf16)(b.w * sc * w[d0 + 7]);
}

__global__ void rope_kernel(bf16* __restrict__ qkv, const float* __restrict__ cosb,
                            const float* __restrict__ sinb, const int* __restrict__ topk) {
  const int r = blockIdx.x;
  const int b = r >> 10;
  const int t = topk[r];
  const float* cr = cosb + ((int64_t)b * cT + t) * cHD;
  const float* sr = sinb + ((int64_t)b * cT + t) * cHD;
  bf16* rowq = qkv + (int64_t)r * QKVW;
  for (int p = threadIdx.x; p < (cH + cKVH) * 64; p += 256) {
    int hh = p >> 6, d = p & 63;
    bf16* base = (hh < cH) ? (rowq + hh * cHD) : (rowq + cH * cHD + (hh - cH) * cHD);
    float x1 = (float)base[d], x2 = (float)base[d + 64];
    float c1 = cr[d], s1 = sr[d], c2 = cr[d + 64], s2 = sr[d + 64];
    base[d] = (bf16)(x1 * c1 - x2 * s1);
    base[d + 64] = (bf16)(x2 * c2 + x1 * s2);
  }
}

__global__ void vtrans(const bf16* __restrict__ qkv, bf16* __restrict__ Vt) {
  __shared__ bf16 t[32][33];
  const int bz = blockIdx.z, b = bz >> 2, kv = bz & 3;
  const int k0 = blockIdx.x * 32, d0 = blockIdx.y * 32;
  for (int rr = threadIdx.y; rr < 32; rr += 8)
    t[rr][threadIdx.x] =
        qkv[(int64_t)(b * cK + k0 + rr) * QKVW + cH * cHD + cKVH * cHD + kv * cHD + d0 + threadIdx.x];
  __syncthreads();
  for (int rr = threadIdx.y; rr < 32; rr += 8)
    Vt[((int64_t)(b * cKVH + kv) * cHD + d0 + rr) * cK + k0 + threadIdx.x] = t[threadIdx.x][rr];
}

}  // namespace

extern "C" void kernel_launch(void* const* d_in, const int* in_sizes, int n_in,
                              void* d_out, int out_size, void* d_ws, size_t ws_size,
                              hipStream_t stream) {
  const float* hidden = (const float*)d_in[0];
  const int* topk = (const int*)d_in[1];
  const float* gating = (const float*)d_in[2];
  const float* cosb = (const float*)d_in[3];
  const float* sinb = (const float*)d_in[4];
  const float* Wq = (const float*)d_in[5];
  const float* bq = (const float*)d_in[6];
  const float* Wk = (const float*)d_in[7];
  const float* bk = (const float*)d_in[8];
  const float* Wv = (const float*)d_in[9];
  const float* bv = (const float*)d_in[10];
  const float* Wo = (const float*)d_in[11];
  const float* wg = (const float*)d_in[12];
  const float* wu = (const float*)d_in[13];
  const float* wd = (const float*)d_in[14];
  const float* ln1 = (const float*)d_in[15];
  const float* ln2 = (const float*)d_in[16];
  float* out = (float*)d_out;
  (void)in_sizes; (void)n_in; (void)out_size; (void)ws_size;

  char* ws = (char*)d_ws;
  size_t off = 0;
  auto alloc = [&](size_t bytes) {
    char* p = ws + off;
    off += (bytes + 255) & ~(size_t)255;
    return p;
  };
  bf16* wt_qkv = (bf16*)alloc((size_t)QKVW * cD * 2);
  bf16* wt_o = (bf16*)alloc((size_t)cD * cD * 2);
  bf16* wt_gu = (bf16*)alloc((size_t)2 * cFF * cD * 2);
  bf16* wt_d = (bf16*)alloc((size_t)cD * cFF * 2);
  float* bias_cat = (float*)alloc((size_t)QKVW * 4);
  bf16* hbuf = (bf16*)alloc((size_t)cM * cD * 2);
  bf16* qkv = (bf16*)alloc((size_t)cM * QKVW * 2);
  bf16* vt = (bf16*)alloc((size_t)cB * cKVH * cHD * cK * 2);
  bf16* attnout = (bf16*)alloc((size_t)cM * cD * 2);
  float* xbuf = (float*)alloc((size_t)cM * cD * 4);
  bf16* actbuf = (bf16*)alloc((size_t)cM * cFF * 2);
  unsigned char* flags = (unsigned char*)alloc((size_t)cB * cT);

  // flags = selected-row mask; copy only unselected rows (down8 writes selected)
  (void)hipMemsetAsync(flags, 0, (size_t)cB * cT, stream);
  build_flags<<<cM / 256, 256, 0, stream>>>(topk, flags);
  copy_skip<<<2048, 256, 0, stream>>>((const float4*)hidden, (float4*)out, flags,
                                      (int64_t)cB * cT * cD / 4);

  const dim3 tb(32, 8);
  wconv<<<dim3(cD / 32, cD / 32), tb, 0, stream>>>(Wq, wt_qkv, cD, cD, 0, cD);
  wconv<<<dim3(512 / 32, cD / 32), tb, 0, stream>>>(Wk, wt_qkv, cD, 512, 2048, cD);
  wconv<<<dim3(512 / 32, cD / 32), tb, 0, stream>>>(Wv, wt_qkv, cD, 512, 2560, cD);
  wconv<<<dim3(cD / 32, cD / 32), tb, 0, stream>>>(Wo, wt_o, cD, cD, 0, cD);
  wconv_gu<<<dim3(cFF / 32, cD / 32, 2), tb, 0, stream>>>(wg, wu, wt_gu);
  wconv<<<dim3(cD / 32, cFF / 32), tb, 0, stream>>>(wd, wt_d, cFF, cD, 0, cFF);
  biascat<<<(QKVW + 255) / 256, 256, 0, stream>>>(bq, bk, bv, bias_cat);

  // gather + rmsnorm1
  rmsnorm_rows<<<cM, 256, 0, stream>>>(hidden, topk, ln1, hbuf);
  // qkv projection (+bias)   [pair-mode pipeline]
  gemm256<256, 2, 4, 5, 2, EpiQKV><<<16 * (QKVW / 256), 512, 0, stream>>>(
      hbuf, cD, wt_qkv, cD, cD, 16, EpiQKV{qkv, bias_cat});
  rope_kernel<<<cM, 256, 0, stream>>>(qkv, cosb, sinb, topk);
  vtrans<<<dim3(cK / 32, cHD / 32, cB * cKVH), tb, 0, stream>>>(qkv, vt);

  // fused flash attention (1D grid, XCD-chunked remap for KV L2 locality)
  flash_attn<<<1024, 256, 0, stream>>>(qkv, vt, attnout);

  // o-proj + gathered residual -> x (fp32)   [pair-mode pipeline]
  gemm256<128, 4, 2, 5, 2, EpiOProj><<<16 * (cD / 128), 512, 0, stream>>>(
      attnout, cD, wt_o, cD, cD, 16, EpiOProj{xbuf, hidden, topk});
  // rmsnorm2
  rmsnorm_rows<<<cM, 256, 0, stream>>>(xbuf, nullptr, ln2, hbuf);
  // fused gate+up -> act = silu(gate)*up   [8-phase m201-style schedule, session best]
  gemm_gateup8<<<16 * (2 * cFF / 256), 512, 0, stream>>>(hbuf, wt_gu, actbuf);
  // down + residual + gating + scatter into d_out   [deep-K 2-phase pipeline]
  gemm_down8<<<256, 512, 0, stream>>>(actbuf, wt_d, out, xbuf, hidden, topk, gating);
}